// Round 1
// baseline (1166.710 us; speedup 1.0000x reference)
//
#include <hip/hip_runtime.h>
#include <math.h>

#define N_TOTAL 30000
#define NPER 10000
#define NEDGE 500000
#define NREL 6
#define SLOPE 0.2f

struct MultiArgs {
  const float* A[3];
  const float* B[3];
  const float* bias[3];
  float* C[3];
  int K[3];
};

// ---------------------------------------------------------------------------
// Generic C[M,128] = A[M,K] @ B[K,128] (+bias) (+ELU), optional fused q/k dots
// Tile: BM=64, BN=128(full), BK=32. Block 256 threads (4 waves).
// ---------------------------------------------------------------------------
template<bool BIAS, bool ELU, bool QK>
__device__ __forceinline__ void gemm_body(
    const float* __restrict__ A, const float* __restrict__ B,
    const float* __restrict__ bias, float* __restrict__ C,
    int M, int K,
    const float* __restrict__ qv, const float* __restrict__ kv,
    float* __restrict__ qd, float* __restrict__ kd, int qdoff)
{
  __shared__ float As[32][68];   // transposed A tile: As[kk][row], pad 68 for 16B-aligned rows
  __shared__ float Bs[32][128];
  const int tid = threadIdx.x;
  const int tx = tid & 31;       // 32 col-groups of 4
  const int ty = tid >> 5;       // 8 row-groups of 8
  const int bm = blockIdx.x * 64;

  float acc[8][4];
  #pragma unroll
  for (int r = 0; r < 8; r++)
    #pragma unroll
    for (int c = 0; c < 4; c++) acc[r][c] = 0.f;

  for (int k0 = 0; k0 < K; k0 += 32) {
    // A tile: 64 rows x 32 k (float2 per load, K always even)
    #pragma unroll
    for (int j = 0; j < 4; j++) {
      int i = tid + j * 256;       // 1024 float2
      int row = i >> 4;            // 16 float2 per row
      int kk = (i & 15) << 1;
      int gr = bm + row;
      int gk = k0 + kk;
      float2 v = make_float2(0.f, 0.f);
      if (gr < M && gk + 1 < K)
        v = *reinterpret_cast<const float2*>(&A[(size_t)gr * K + gk]);
      As[kk][row] = v.x;
      As[kk + 1][row] = v.y;
    }
    // B tile: 32 rows x 128 (float4)
    #pragma unroll
    for (int j = 0; j < 4; j++) {
      int i = tid + j * 256;       // 1024 float4
      int row = i >> 5;            // 32 float4 per row
      int c4 = (i & 31) << 2;
      int gk = k0 + row;
      float4 v = make_float4(0.f, 0.f, 0.f, 0.f);
      if (gk < K)
        v = *reinterpret_cast<const float4*>(&B[(size_t)gk * 128 + c4]);
      *reinterpret_cast<float4*>(&Bs[row][c4]) = v;
    }
    __syncthreads();
    #pragma unroll
    for (int kk = 0; kk < 32; kk++) {
      float4 a0 = *reinterpret_cast<const float4*>(&As[kk][ty * 8]);
      float4 a1 = *reinterpret_cast<const float4*>(&As[kk][ty * 8 + 4]);
      float4 bv = *reinterpret_cast<const float4*>(&Bs[kk][tx * 4]);
      float ar[8] = {a0.x, a0.y, a0.z, a0.w, a1.x, a1.y, a1.z, a1.w};
      float br[4] = {bv.x, bv.y, bv.z, bv.w};
      #pragma unroll
      for (int r = 0; r < 8; r++)
        #pragma unroll
        for (int c = 0; c < 4; c++)
          acc[r][c] = fmaf(ar[r], br[c], acc[r][c]);
    }
    __syncthreads();
  }

  float bq[4], bk2[4];
  if (QK) {
    bq[0] = qv[tx * 4]; bq[1] = qv[tx * 4 + 1]; bq[2] = qv[tx * 4 + 2]; bq[3] = qv[tx * 4 + 3];
    bk2[0] = kv[tx * 4]; bk2[1] = kv[tx * 4 + 1]; bk2[2] = kv[tx * 4 + 2]; bk2[3] = kv[tx * 4 + 3];
  }
  float bb[4];
  if (BIAS) {
    bb[0] = bias[tx * 4]; bb[1] = bias[tx * 4 + 1]; bb[2] = bias[tx * 4 + 2]; bb[3] = bias[tx * 4 + 3];
  }
  #pragma unroll
  for (int r = 0; r < 8; r++) {
    int gr = bm + ty * 8 + r;
    bool valid = gr < M;   // uniform across each 32-lane group (same ty)
    if (QK) {
      float qp = acc[r][0]*bq[0] + acc[r][1]*bq[1] + acc[r][2]*bq[2] + acc[r][3]*bq[3];
      float kp = acc[r][0]*bk2[0] + acc[r][1]*bk2[1] + acc[r][2]*bk2[2] + acc[r][3]*bk2[3];
      #pragma unroll
      for (int mm = 16; mm; mm >>= 1) { qp += __shfl_xor(qp, mm); kp += __shfl_xor(kp, mm); }
      if (tx == 0 && valid) { qd[qdoff + gr] = qp; kd[qdoff + gr] = kp; }
    }
    if (valid) {
      float o[4];
      #pragma unroll
      for (int c = 0; c < 4; c++) {
        float v = acc[r][c];
        if (BIAS) v += bb[c];
        if (ELU) v = v > 0.f ? v : expm1f(v);
        o[c] = v;
      }
      *reinterpret_cast<float4*>(&C[(size_t)gr * 128 + tx * 4]) =
          make_float4(o[0], o[1], o[2], o[3]);
    }
  }
}

template<bool BIAS, bool ELU, bool QK>
__global__ __launch_bounds__(256, 2)
void gemm_batched(const float* __restrict__ A, const float* __restrict__ B,
                  const float* __restrict__ bias, float* __restrict__ C,
                  int M, int K, long long sB, long long sC,
                  const float* __restrict__ qv, const float* __restrict__ kv,
                  float* __restrict__ qd, float* __restrict__ kd, int nPerBatch)
{
  int z = blockIdx.z;
  gemm_body<BIAS, ELU, QK>(A, B + z * sB, bias, C + z * sC, M, K,
                           qv, kv, qd, kd, z * nPerBatch);
}

template<bool BIAS, bool ELU>
__global__ __launch_bounds__(256, 2)
void gemm_multi(MultiArgs ma, int M)
{
  int z = blockIdx.z;
  gemm_body<BIAS, ELU, false>(ma.A[z], ma.B[z], ma.bias[z], ma.C[z], M, ma.K[z],
                              nullptr, nullptr, nullptr, nullptr, 0);
}

// ---------------------------------------------------------------------------
// Edge / segment kernels
// ---------------------------------------------------------------------------
__global__ __launch_bounds__(256)
void init_kernel(int* __restrict__ m_int, float* __restrict__ s,
                 float* __restrict__ deg, float* __restrict__ agg)
{
  int i = blockIdx.x * 256 + threadIdx.x;
  if (i < N_TOTAL) { m_int[i] = (int)0x80000000; s[i] = 0.f; deg[i] = 0.f; }
  if (i < N_TOTAL * 128) agg[i] = 0.f;
}

__device__ __forceinline__ int f2ord(float f) {
  int i = __float_as_int(f);
  return (i >= 0) ? i : (i ^ 0x7fffffff);
}
__device__ __forceinline__ float ord2f(int i) {
  return __int_as_float((i >= 0) ? i : (i ^ 0x7fffffff));
}

__global__ __launch_bounds__(256)
void edge_alpha(const int* __restrict__ src, const int* __restrict__ dst,
                const int* __restrict__ et,
                const float* __restrict__ qd, const float* __restrict__ kd,
                float* __restrict__ alpha, int* __restrict__ m_int,
                float* __restrict__ deg)
{
  int e = blockIdx.x * 256 + threadIdx.x;
  if (e >= NEDGE) return;
  int t = et[e], d = dst[e], sn = src[e];
  float a = qd[t * N_TOTAL + d] + kd[t * N_TOTAL + sn];
  a = (a > 0.f) ? a : SLOPE * a;
  alpha[e] = a;
  atomicMax(&m_int[d], f2ord(a));
  atomicAdd(&deg[d], 1.0f);
}

__global__ __launch_bounds__(256)
void edge_expsum(const int* __restrict__ dst, const float* __restrict__ alpha,
                 const int* __restrict__ m_int, float* __restrict__ s)
{
  int e = blockIdx.x * 256 + threadIdx.x;
  if (e >= NEDGE) return;
  int d = dst[e];
  float m = ord2f(m_int[d]);
  atomicAdd(&s[d], expf(alpha[e] - m));
}

__global__ __launch_bounds__(256)
void edge_scatter(const int* __restrict__ src, const int* __restrict__ dst,
                  const int* __restrict__ et, const float* __restrict__ alpha,
                  const int* __restrict__ m_int, const float* __restrict__ s,
                  const float* __restrict__ deg, const float* __restrict__ xw,
                  float* __restrict__ agg)
{
  int e = blockIdx.x * 2 + (threadIdx.x >> 7);
  int d0 = threadIdx.x & 127;
  if (e >= NEDGE) return;
  int d = dst[e], t = et[e], sn = src[e];
  float m = ord2f(m_int[d]);
  float coef = expf(alpha[e] - m) / s[d] * deg[d];
  float v = xw[((size_t)t * N_TOTAL + sn) * 128 + d0];
  atomicAdd(&agg[(size_t)d * 128 + d0], coef * v);
}

__global__ __launch_bounds__(256)
void combine_kernel(const float* __restrict__ agg, const float* __restrict__ sl,
                    const float* __restrict__ b, float* __restrict__ h)
{
  int i = blockIdx.x * 256 + threadIdx.x;
  if (i >= N_TOTAL * 128) return;
  float v = agg[i] + b[i & 127] + sl[i];
  h[i] = v > 0.f ? v : expm1f(v);
}

__global__ __launch_bounds__(256)
void lin2_kernel(const float* __restrict__ z, const float* __restrict__ W,
                 const float* __restrict__ b, float* __restrict__ out)
{
  int row = blockIdx.x * 4 + (threadIdx.x >> 6);
  int lane = threadIdx.x & 63;
  if (row >= NPER) return;
  float p[5] = {0.f, 0.f, 0.f, 0.f, 0.f};
  #pragma unroll
  for (int h = 0; h < 2; h++) {
    int kidx = lane + h * 64;
    float zv = z[(size_t)row * 128 + kidx];
    #pragma unroll
    for (int j = 0; j < 5; j++) p[j] = fmaf(zv, W[kidx * 5 + j], p[j]);
  }
  #pragma unroll
  for (int mm = 32; mm; mm >>= 1)
    #pragma unroll
    for (int j = 0; j < 5; j++) p[j] += __shfl_xor(p[j], mm);
  if (lane == 0) {
    #pragma unroll
    for (int j = 0; j < 5; j++) out[(size_t)row * 5 + j] = p[j] + b[j];
  }
}

// ---------------------------------------------------------------------------
extern "C" void kernel_launch(void* const* d_in, const int* in_sizes, int n_in,
                              void* d_out, int out_size, void* d_ws, size_t ws_size,
                              hipStream_t stream) {
  const float* x0 = (const float*)d_in[0];
  const float* x1 = (const float*)d_in[1];
  const float* x2 = (const float*)d_in[2];
  const float* projW[3] = {(const float*)d_in[3], (const float*)d_in[5], (const float*)d_in[7]};
  const float* projb[3] = {(const float*)d_in[4], (const float*)d_in[6], (const float*)d_in[8]};
  const float* slW[3]   = {(const float*)d_in[9], (const float*)d_in[11], (const float*)d_in[13]};
  const float* slb[3]   = {(const float*)d_in[10], (const float*)d_in[12], (const float*)d_in[14]};
  const float* W1 = (const float*)d_in[15];
  const float* q1 = (const float*)d_in[16];
  const float* k1 = (const float*)d_in[17];
  const float* b1 = (const float*)d_in[18];
  const float* W2 = (const float*)d_in[19];
  const float* q2 = (const float*)d_in[20];
  const float* k2 = (const float*)d_in[21];
  const float* b2 = (const float*)d_in[22];
  const float* lin1W = (const float*)d_in[23];
  const float* lin1b = (const float*)d_in[24];
  const float* lin2W = (const float*)d_in[25];
  const float* lin2b = (const float*)d_in[26];
  const int* esrc = (const int*)d_in[27];
  const int* edst = (const int*)d_in[28];
  const int* etyp = (const int*)d_in[29];

  float* ws = (float*)d_ws;
  size_t off = 0;
  float* X   = ws + off; off += (size_t)N_TOTAL * 128;
  float* SL  = ws + off; off += (size_t)N_TOTAL * 128;
  float* XW  = ws + off; off += (size_t)NREL * N_TOTAL * 128;
  float* AGG = ws + off; off += (size_t)N_TOTAL * 128;
  float* H   = ws + off; off += (size_t)N_TOTAL * 128;
  float* QD  = ws + off; off += (size_t)NREL * N_TOTAL;
  float* KD  = ws + off; off += (size_t)NREL * N_TOTAL;
  float* ALPHA = ws + off; off += (size_t)NEDGE;
  int*   MI  = (int*)(ws + off); off += (size_t)N_TOTAL;
  float* S   = ws + off; off += (size_t)N_TOTAL;
  float* DEG = ws + off; off += (size_t)N_TOTAL;
  float* Z   = ws + off; off += (size_t)NPER * 128;

  const int gridM_per = (NPER + 63) / 64;     // 157
  const int gridM_tot = (N_TOTAL + 63) / 64;  // 469
  const int gridE = (NEDGE + 255) / 256;      // 1954
  const int gridNode = (N_TOTAL * 128 + 255) / 256; // 15000

  // per-omic projections: xp_i = elu(x_i @ projW_i + projb_i)
  {
    MultiArgs ma;
    const float* xs[3] = {x0, x1, x2};
    int Ks[3] = {2000, 1500, 1000};
    for (int i = 0; i < 3; i++) {
      ma.A[i] = xs[i]; ma.B[i] = projW[i]; ma.bias[i] = projb[i];
      ma.C[i] = X + (size_t)i * NPER * 128; ma.K[i] = Ks[i];
    }
    gemm_multi<true, true><<<dim3(gridM_per, 1, 3), 256, 0, stream>>>(ma, NPER);
  }
  // self-loop: sl_i = xp_i @ slW_i + slb_i
  {
    MultiArgs ma;
    for (int i = 0; i < 3; i++) {
      ma.A[i] = X + (size_t)i * NPER * 128; ma.B[i] = slW[i]; ma.bias[i] = slb[i];
      ma.C[i] = SL + (size_t)i * NPER * 128; ma.K[i] = 128;
    }
    gemm_multi<true, false><<<dim3(gridM_per, 1, 3), 256, 0, stream>>>(ma, NPER);
  }

  // ---- RGAT layer 1 ----
  gemm_batched<false, false, true><<<dim3(gridM_tot, 1, NREL), 256, 0, stream>>>(
      X, W1, nullptr, XW, N_TOTAL, 128, 128LL * 128, (long long)N_TOTAL * 128,
      q1, k1, QD, KD, N_TOTAL);
  init_kernel<<<gridNode, 256, 0, stream>>>(MI, S, DEG, AGG);
  edge_alpha<<<gridE, 256, 0, stream>>>(esrc, edst, etyp, QD, KD, ALPHA, MI, DEG);
  edge_expsum<<<gridE, 256, 0, stream>>>(edst, ALPHA, MI, S);
  edge_scatter<<<NEDGE / 2, 256, 0, stream>>>(esrc, edst, etyp, ALPHA, MI, S, DEG, XW, AGG);
  combine_kernel<<<gridNode, 256, 0, stream>>>(AGG, SL, b1, H);

  // ---- RGAT layer 2 ----
  gemm_batched<false, false, true><<<dim3(gridM_tot, 1, NREL), 256, 0, stream>>>(
      H, W2, nullptr, XW, N_TOTAL, 128, 128LL * 128, (long long)N_TOTAL * 128,
      q2, k2, QD, KD, N_TOTAL);
  init_kernel<<<gridNode, 256, 0, stream>>>(MI, S, DEG, AGG);
  edge_alpha<<<gridE, 256, 0, stream>>>(esrc, edst, etyp, QD, KD, ALPHA, MI, DEG);
  edge_expsum<<<gridE, 256, 0, stream>>>(edst, ALPHA, MI, S);
  edge_scatter<<<NEDGE / 2, 256, 0, stream>>>(esrc, edst, etyp, ALPHA, MI, S, DEG, XW, AGG);
  combine_kernel<<<gridNode, 256, 0, stream>>>(AGG, SL, b2, H);

  // ---- head ----
  gemm_batched<true, true, false><<<dim3(gridM_per, 1, 1), 256, 0, stream>>>(
      H, lin1W, lin1b, Z, NPER, 128, 0, 0, nullptr, nullptr, nullptr, nullptr, 0);
  lin2_kernel<<<(NPER + 3) / 4, 256, 0, stream>>>(Z, lin2W, lin2b, (float*)d_out);
}

// Round 3
// 885.404 us; speedup vs baseline: 1.3177x; 1.3177x over previous
//
#include <hip/hip_runtime.h>
#include <math.h>

#define N_TOTAL 30000
#define NPER 10000
#define NEDGE 500000
#define NREL 6
#define SLOPE 0.2f

typedef __attribute__((ext_vector_type(4))) float f32x4;
typedef __attribute__((ext_vector_type(8))) short s16x8;
typedef __attribute__((ext_vector_type(4))) short s16x4;
typedef unsigned short u16;
typedef unsigned int u32;

__device__ __forceinline__ u16 f2bf(float v) {
  u32 x = __float_as_uint(v);
  u32 r = (x + 0x7fffu + ((x >> 16) & 1u)) >> 16;  // RNE
  return (u16)r;
}
__device__ __forceinline__ float bf2f(u16 u) {
  return __uint_as_float(((u32)u) << 16);
}

// ---------------------------------------------------------------------------
// Split-precision bf16 MFMA GEMM: C[M,128] = A[M,K](f32) @ B[K,128] (+bias)(+ELU)
// A staged as hi/lo bf16 pair -> 2 MFMAs per fragment: ~f32-accurate products,
// only B (weight) rounding remains.
// Tile BM=64, BN=128, BK=64. 256 threads = 4 waves (2x2), wave tile 32x64.
// LDS XOR-swizzled (byte ^= (row&7)<<4) so ds_read_b128 frags are conflict-free.
// C/D frag: col=lane&15, row=(lane>>4)*4+reg  [guide m89/m91 verified].
// ---------------------------------------------------------------------------
struct GB {
  const float* A[6];
  const u16* Bt[6];     // [128][Kp] bf16, transposed, zero-padded to Kp
  const float* bias[6];
  void* C[6];
  int K[6];             // real K (A row stride / bounds)
  int Kp[6];            // padded K (Bt stride, loop bound)
};

template<bool BIAS, bool ELU, bool OBF>
__global__ __launch_bounds__(256, 2)
void gemm_mfma(GB gb, int M)
{
  __shared__ char As[64 * 128];     // hi tile: 64 rows x 64 bf16 (swizzled)
  __shared__ char Aslo[64 * 128];   // lo tile
  __shared__ char Bs[128 * 128];    // 128 n-rows x 64 bf16 (swizzled)
  const int z = blockIdx.z;
  const int K = gb.K[z], Kp = gb.Kp[z];
  const int tid = threadIdx.x;
  const int bm = blockIdx.x * 64;
  const int lane = tid & 63;
  const int wave = tid >> 6;
  const int wr = wave >> 1, wc = wave & 1;
  const int lane16 = lane & 15, lhalf = lane >> 4;
  const float* A = gb.A[z];
  const u16* Bt = gb.Bt[z];

  f32x4 acc[2][4];
  #pragma unroll
  for (int mi = 0; mi < 2; mi++)
    #pragma unroll
    for (int ni = 0; ni < 4; ni++)
      #pragma unroll
      for (int q = 0; q < 4; q++) acc[mi][ni][q] = 0.f;

  for (int k0 = 0; k0 < Kp; k0 += 64) {
    // ---- stage A tile (64 rows x 64 k, f32 -> hi/lo bf16) ----
    #pragma unroll
    for (int it = 0; it < 4; it++) {
      int idx = tid + it * 256;        // 1024 float4 units
      int row = idx >> 4;              // 16 float4 per row
      int kc = (idx & 15) << 2;
      int gr = bm + row, gk = k0 + kc;
      float4 v = make_float4(0.f, 0.f, 0.f, 0.f);
      if (gr < M && gk < K) v = *(const float4*)&A[(size_t)gr * K + gk];
      s16x4 hi, lo;
      float vv[4] = {v.x, v.y, v.z, v.w};
      #pragma unroll
      for (int j = 0; j < 4; j++) {
        u16 h = f2bf(vv[j]);
        hi[j] = (short)h;
        lo[j] = (short)f2bf(vv[j] - bf2f(h));
      }
      int boff = row * 128 + ((kc * 2) ^ ((row & 7) << 4));
      *(s16x4*)(As + boff) = hi;
      *(s16x4*)(Aslo + boff) = lo;
    }
    // ---- stage B tile (128 n-rows x 64 k), Bt zero-padded to Kp ----
    #pragma unroll
    for (int it = 0; it < 4; it++) {
      int idx = tid + it * 256;          // 1024 x 16B chunks
      int row = idx >> 3;
      int kc = (idx & 7) << 3;
      s16x8 v = *(const s16x8*)&Bt[(size_t)row * Kp + k0 + kc];
      *(s16x8*)(Bs + row * 128 + ((kc * 2) ^ ((row & 7) << 4))) = v;
    }
    __syncthreads();
    #pragma unroll
    for (int kk = 0; kk < 2; kk++) {
      const int kbyte = kk * 64 + lhalf * 16;
      s16x8 afh[2], afl[2], bfr[4];
      #pragma unroll
      for (int mi = 0; mi < 2; mi++) {
        int row = wr * 32 + mi * 16 + lane16;
        int boff = row * 128 + (kbyte ^ ((row & 7) << 4));
        afh[mi] = *(const s16x8*)(As + boff);
        afl[mi] = *(const s16x8*)(Aslo + boff);
      }
      #pragma unroll
      for (int ni = 0; ni < 4; ni++) {
        int row = wc * 64 + ni * 16 + lane16;
        bfr[ni] = *(const s16x8*)(Bs + row * 128 + (kbyte ^ ((row & 7) << 4)));
      }
      #pragma unroll
      for (int mi = 0; mi < 2; mi++)
        #pragma unroll
        for (int ni = 0; ni < 4; ni++) {
          acc[mi][ni] = __builtin_amdgcn_mfma_f32_16x16x32_bf16(
              afl[mi], bfr[ni], acc[mi][ni], 0, 0, 0);
          acc[mi][ni] = __builtin_amdgcn_mfma_f32_16x16x32_bf16(
              afh[mi], bfr[ni], acc[mi][ni], 0, 0, 0);
        }
    }
    __syncthreads();
  }

  float bcol[4];
  #pragma unroll
  for (int ni = 0; ni < 4; ni++) {
    int col = wc * 64 + ni * 16 + lane16;
    if (BIAS) bcol[ni] = gb.bias[z][col];
  }
  #pragma unroll
  for (int mi = 0; mi < 2; mi++) {
    #pragma unroll
    for (int q = 0; q < 4; q++) {
      int grow = bm + wr * 32 + mi * 16 + lhalf * 4 + q;
      if (grow < M) {
        #pragma unroll
        for (int ni = 0; ni < 4; ni++) {
          float v = acc[mi][ni][q];
          if (BIAS) v += bcol[ni];
          if (ELU) v = v > 0.f ? v : expm1f(v);
          int col = wc * 64 + ni * 16 + lane16;
          if (OBF) ((u16*)gb.C[z])[(size_t)grow * 128 + col] = f2bf(v);
          else     ((float*)gb.C[z])[(size_t)grow * 128 + col] = v;
        }
      }
    }
  }
}

// ---------------------------------------------------------------------------
// Weight convert: src f32 [K][128] -> dst bf16 [128][Kp] (transposed, padded)
// ---------------------------------------------------------------------------
struct CW {
  const float* src[19];
  u16* dst[19];
  int K[19];
  int Kp[19];
};

__global__ __launch_bounds__(256)
void conv_w(CW cw) {
  int z = blockIdx.z;
  int K = cw.K[z], Kp = cw.Kp[z];
  int idx = blockIdx.x * 256 + threadIdx.x;
  if (idx >= 128 * Kp) return;
  int kq = idx >> 7, n = idx & 127;
  cw.dst[z][(size_t)n * Kp + kq] =
      (kq < K) ? f2bf(cw.src[z][(size_t)kq * 128 + n]) : (u16)0;
}

// ---------------------------------------------------------------------------
// Attention-score precompute: Wq[r] = W[r] @ q  (exact f32; associativity:
// (x@W)@q == x@(W@q)), then QD[r,n] = X[n,:] . Wq[r].
// ---------------------------------------------------------------------------
__global__ __launch_bounds__(128)
void wqk_kernel(const float* __restrict__ W, const float* __restrict__ q,
                const float* __restrict__ k, float* __restrict__ wq,
                float* __restrict__ wk)
{
  int r = blockIdx.x;
  int t = threadIdx.x;
  const float* Wr = W + (size_t)r * 128 * 128 + (size_t)t * 128;
  float aq = 0.f, ak = 0.f;
  for (int o = 0; o < 128; o++) {
    float w = Wr[o];
    aq = fmaf(w, q[o], aq);
    ak = fmaf(w, k[o], ak);
  }
  wq[r * 128 + t] = aq;
  wk[r * 128 + t] = ak;
}

__global__ __launch_bounds__(256)
void qdkd_kernel(const float* __restrict__ Xf, const float* __restrict__ wq,
                 const float* __restrict__ wk, float* __restrict__ QD,
                 float* __restrict__ KD)
{
  __shared__ float sq[NREL * 128], sk[NREL * 128];
  for (int i = threadIdx.x; i < NREL * 128; i += 256) { sq[i] = wq[i]; sk[i] = wk[i]; }
  __syncthreads();
  int n = blockIdx.x * 256 + threadIdx.x;
  if (n >= N_TOTAL) return;
  float aq[NREL], ak[NREL];
  #pragma unroll
  for (int r = 0; r < NREL; r++) { aq[r] = 0.f; ak[r] = 0.f; }
  for (int kc = 0; kc < 128; kc += 4) {
    float4 x = *(const float4*)&Xf[(size_t)n * 128 + kc];
    #pragma unroll
    for (int r = 0; r < NREL; r++) {
      aq[r] += x.x * sq[r * 128 + kc] + x.y * sq[r * 128 + kc + 1]
             + x.z * sq[r * 128 + kc + 2] + x.w * sq[r * 128 + kc + 3];
      ak[r] += x.x * sk[r * 128 + kc] + x.y * sk[r * 128 + kc + 1]
             + x.z * sk[r * 128 + kc + 2] + x.w * sk[r * 128 + kc + 3];
    }
  }
  #pragma unroll
  for (int r = 0; r < NREL; r++) {
    QD[(size_t)r * N_TOTAL + n] = aq[r];
    KD[(size_t)r * N_TOTAL + n] = ak[r];
  }
}

// ---------------------------------------------------------------------------
// Edge / segment kernels
// ---------------------------------------------------------------------------
__global__ __launch_bounds__(256)
void init_kernel(int* __restrict__ m_int, float* __restrict__ s,
                 float* __restrict__ deg, float* __restrict__ agg)
{
  int i = blockIdx.x * 256 + threadIdx.x;
  if (i < N_TOTAL) { m_int[i] = (int)0x80000000; s[i] = 0.f; deg[i] = 0.f; }
  if (i < N_TOTAL * 128) agg[i] = 0.f;
}

__device__ __forceinline__ int f2ord(float f) {
  int i = __float_as_int(f);
  return (i >= 0) ? i : (i ^ 0x7fffffff);
}
__device__ __forceinline__ float ord2f(int i) {
  return __int_as_float((i >= 0) ? i : (i ^ 0x7fffffff));
}

__global__ __launch_bounds__(256)
void edge_alpha(const int* __restrict__ src, const int* __restrict__ dst,
                const int* __restrict__ et,
                const float* __restrict__ qd, const float* __restrict__ kd,
                float* __restrict__ alpha, int* __restrict__ m_int,
                float* __restrict__ deg)
{
  int e = blockIdx.x * 256 + threadIdx.x;
  if (e >= NEDGE) return;
  int t = et[e], d = dst[e], sn = src[e];
  float a = qd[t * N_TOTAL + d] + kd[t * N_TOTAL + sn];
  a = (a > 0.f) ? a : SLOPE * a;
  alpha[e] = a;
  atomicMax(&m_int[d], f2ord(a));
  atomicAdd(&deg[d], 1.0f);
}

__global__ __launch_bounds__(256)
void edge_expsum(const int* __restrict__ dst, const float* __restrict__ alpha,
                 const int* __restrict__ m_int, float* __restrict__ s)
{
  int e = blockIdx.x * 256 + threadIdx.x;
  if (e >= NEDGE) return;
  int d = dst[e];
  float m = ord2f(m_int[d]);
  atomicAdd(&s[d], expf(alpha[e] - m));
}

template<bool XF32>
__global__ __launch_bounds__(256)
void edge_scatter(const int* __restrict__ src, const int* __restrict__ dst,
                  const int* __restrict__ et, const float* __restrict__ alpha,
                  const int* __restrict__ m_int, const float* __restrict__ s,
                  const float* __restrict__ deg, const void* __restrict__ xw,
                  float* __restrict__ agg)
{
  int e = blockIdx.x * 2 + (threadIdx.x >> 7);
  int d0 = threadIdx.x & 127;
  if (e >= NEDGE) return;
  int d = dst[e], t = et[e], sn = src[e];
  float m = ord2f(m_int[d]);
  float coef = expf(alpha[e] - m) / s[d] * deg[d];
  size_t idx = ((size_t)t * N_TOTAL + sn) * 128 + d0;
  float v = XF32 ? ((const float*)xw)[idx] : bf2f(((const u16*)xw)[idx]);
  atomicAdd(&agg[(size_t)d * 128 + d0], coef * v);
}

__global__ __launch_bounds__(256)
void combine_kernel(const float* __restrict__ agg, const float* __restrict__ sl,
                    const float* __restrict__ b, float* __restrict__ h)
{
  int i = blockIdx.x * 256 + threadIdx.x;
  if (i >= N_TOTAL * 128) return;
  float v = agg[i] + b[i & 127] + sl[i];
  h[i] = v > 0.f ? v : expm1f(v);
}

__global__ __launch_bounds__(256)
void lin2_kernel(const float* __restrict__ z, const float* __restrict__ W,
                 const float* __restrict__ b, float* __restrict__ out)
{
  int row = blockIdx.x * 4 + (threadIdx.x >> 6);
  int lane = threadIdx.x & 63;
  if (row >= NPER) return;
  float p[5] = {0.f, 0.f, 0.f, 0.f, 0.f};
  #pragma unroll
  for (int h = 0; h < 2; h++) {
    int kidx = lane + h * 64;
    float zv = z[(size_t)row * 128 + kidx];
    #pragma unroll
    for (int j = 0; j < 5; j++) p[j] = fmaf(zv, W[kidx * 5 + j], p[j]);
  }
  #pragma unroll
  for (int mm = 32; mm; mm >>= 1)
    #pragma unroll
    for (int j = 0; j < 5; j++) p[j] += __shfl_xor(p[j], mm);
  if (lane == 0) {
    #pragma unroll
    for (int j = 0; j < 5; j++) out[(size_t)row * 5 + j] = p[j] + b[j];
  }
}

// ---------------------------------------------------------------------------
extern "C" void kernel_launch(void* const* d_in, const int* in_sizes, int n_in,
                              void* d_out, int out_size, void* d_ws, size_t ws_size,
                              hipStream_t stream) {
  const float* xs[3] = {(const float*)d_in[0], (const float*)d_in[1], (const float*)d_in[2]};
  const float* projW[3] = {(const float*)d_in[3], (const float*)d_in[5], (const float*)d_in[7]};
  const float* projb[3] = {(const float*)d_in[4], (const float*)d_in[6], (const float*)d_in[8]};
  const float* slW[3]   = {(const float*)d_in[9], (const float*)d_in[11], (const float*)d_in[13]};
  const float* slb[3]   = {(const float*)d_in[10], (const float*)d_in[12], (const float*)d_in[14]};
  const float* W1 = (const float*)d_in[15];
  const float* q1 = (const float*)d_in[16];
  const float* k1 = (const float*)d_in[17];
  const float* b1 = (const float*)d_in[18];
  const float* W2 = (const float*)d_in[19];
  const float* q2 = (const float*)d_in[20];
  const float* k2 = (const float*)d_in[21];
  const float* b2 = (const float*)d_in[22];
  const float* lin1W = (const float*)d_in[23];
  const float* lin1b = (const float*)d_in[24];
  const float* lin2W = (const float*)d_in[25];
  const float* lin2b = (const float*)d_in[26];
  const int* esrc = (const int*)d_in[27];
  const int* edst = (const int*)d_in[28];
  const int* etyp = (const int*)d_in[29];

  char* wp = (char*)d_ws;
  auto alloc = [&](size_t bytes) -> char* {
    char* p = wp; wp += (bytes + 255) & ~(size_t)255; return p;
  };
  float* Xf  = (float*)alloc((size_t)N_TOTAL * 128 * 4);
  float* SL  = (float*)alloc((size_t)N_TOTAL * 128 * 4);
  float* AGG = (float*)alloc((size_t)N_TOTAL * 128 * 4);
  float* Hf  = (float*)alloc((size_t)N_TOTAL * 128 * 4);
  float* QD  = (float*)alloc((size_t)NREL * N_TOTAL * 4);
  float* KD  = (float*)alloc((size_t)NREL * N_TOTAL * 4);
  float* ALPHA = (float*)alloc((size_t)NEDGE * 4);
  int*   MI  = (int*)  alloc((size_t)N_TOTAL * 4);
  float* S   = (float*)alloc((size_t)N_TOTAL * 4);
  float* DEG = (float*)alloc((size_t)N_TOTAL * 4);
  float* Z   = (float*)alloc((size_t)NPER * 128 * 4);
  float* WQ1 = (float*)alloc((size_t)NREL * 128 * 4);
  float* WK1 = (float*)alloc((size_t)NREL * 128 * 4);
  float* WQ2 = (float*)alloc((size_t)NREL * 128 * 4);
  float* WK2 = (float*)alloc((size_t)NREL * 128 * 4);

  // ---- weight conversion table (transposed + K padded to 64) ----
  CW cw;
  int nW = 0;
  auto addW = [&](const float* src, int K) {
    int Kp = (K + 63) & ~63;
    cw.src[nW] = src; cw.K[nW] = K; cw.Kp[nW] = Kp;
    cw.dst[nW] = (u16*)alloc((size_t)128 * Kp * 2);
    nW++;
  };
  addW(projW[0], 2000); addW(projW[1], 1500); addW(projW[2], 1000);
  addW(slW[0], 128); addW(slW[1], 128); addW(slW[2], 128);
  for (int r = 0; r < NREL; r++) addW(W1 + (size_t)r * 128 * 128, 128);
  for (int r = 0; r < NREL; r++) addW(W2 + (size_t)r * 128 * 128, 128);
  addW(lin1W, 128);   // nW == 19

  // XW last: f32 if workspace allows, else bf16
  size_t used = (size_t)(wp - (char*)d_ws);
  size_t xw_f32_bytes = (size_t)NREL * N_TOTAL * 128 * 4;
  bool xwf32 = (ws_size >= used + xw_f32_bytes + 4096);
  void* XW = (void*)alloc(xwf32 ? xw_f32_bytes : xw_f32_bytes / 2);

  const int gridM_per = (NPER + 63) / 64;     // 157
  const int gridM_tot = (N_TOTAL + 63) / 64;  // 469
  const int gridE = (NEDGE + 255) / 256;
  const int gridNode = (N_TOTAL * 128 + 255) / 256;
  const int gridN = (N_TOTAL + 255) / 256;

  conv_w<<<dim3(1024, 1, 19), 256, 0, stream>>>(cw);
  wqk_kernel<<<NREL, 128, 0, stream>>>(W1, q1, k1, WQ1, WK1);
  wqk_kernel<<<NREL, 128, 0, stream>>>(W2, q2, k2, WQ2, WK2);

  // ---- projections: Xf = elu(x_i @ projW_i + projb_i) (f32) ----
  {
    GB g;
    for (int z = 0; z < 3; z++) {
      g.A[z] = xs[z]; g.Bt[z] = cw.dst[z]; g.bias[z] = projb[z];
      g.C[z] = Xf + (size_t)z * NPER * 128;
      g.K[z] = cw.K[z]; g.Kp[z] = cw.Kp[z];
    }
    gemm_mfma<true, true, false><<<dim3(gridM_per, 1, 3), 256, 0, stream>>>(g, NPER);
  }
  // ---- self-loops: SL = Xf_i @ slW_i + slb_i (f32) ----
  {
    GB g;
    for (int z = 0; z < 3; z++) {
      g.A[z] = Xf + (size_t)z * NPER * 128; g.Bt[z] = cw.dst[3 + z];
      g.bias[z] = slb[z]; g.C[z] = SL + (size_t)z * NPER * 128;
      g.K[z] = 128; g.Kp[z] = 128;
    }
    gemm_mfma<true, false, false><<<dim3(gridM_per, 1, 3), 256, 0, stream>>>(g, NPER);
  }

  for (int layer = 0; layer < 2; layer++) {
    const float* Ain = (layer == 0) ? Xf : Hf;
    const float* WQ = (layer == 0) ? WQ1 : WQ2;
    const float* WK = (layer == 0) ? WK1 : WK2;
    const float* bb = (layer == 0) ? b1 : b2;
    int wbase = (layer == 0) ? 6 : 12;

    init_kernel<<<gridNode, 256, 0, stream>>>(MI, S, DEG, AGG);
    qdkd_kernel<<<gridN, 256, 0, stream>>>(Ain, WQ, WK, QD, KD);
    {
      GB g;
      for (int z = 0; z < NREL; z++) {
        g.A[z] = Ain; g.Bt[z] = cw.dst[wbase + z]; g.bias[z] = nullptr;
        if (xwf32) g.C[z] = (float*)XW + (size_t)z * N_TOTAL * 128;
        else       g.C[z] = (u16*)XW + (size_t)z * N_TOTAL * 128;
        g.K[z] = 128; g.Kp[z] = 128;
      }
      if (xwf32)
        gemm_mfma<false, false, false><<<dim3(gridM_tot, 1, NREL), 256, 0, stream>>>(g, N_TOTAL);
      else
        gemm_mfma<false, false, true><<<dim3(gridM_tot, 1, NREL), 256, 0, stream>>>(g, N_TOTAL);
    }
    edge_alpha<<<gridE, 256, 0, stream>>>(esrc, edst, etyp, QD, KD, ALPHA, MI, DEG);
    edge_expsum<<<gridE, 256, 0, stream>>>(edst, ALPHA, MI, S);
    if (xwf32)
      edge_scatter<true><<<NEDGE / 2, 256, 0, stream>>>(esrc, edst, etyp, ALPHA, MI, S, DEG, XW, AGG);
    else
      edge_scatter<false><<<NEDGE / 2, 256, 0, stream>>>(esrc, edst, etyp, ALPHA, MI, S, DEG, XW, AGG);
    combine_kernel<<<gridNode, 256, 0, stream>>>(AGG, SL, bb, Hf);
  }

  // ---- head: Z = elu(Hf[:NPER] @ lin1W + lin1b); out = Z @ lin2W + lin2b ----
  {
    GB g;
    g.A[0] = Hf; g.Bt[0] = cw.dst[18]; g.bias[0] = lin1b; g.C[0] = Z;
    g.K[0] = 128; g.Kp[0] = 128;
    gemm_mfma<true, true, false><<<dim3(gridM_per, 1, 1), 256, 0, stream>>>(g, NPER);
  }
  lin2_kernel<<<(NPER + 3) / 4, 256, 0, stream>>>(Z, lin2W, lin2b, (float*)d_out);
}

// Round 4
// 513.692 us; speedup vs baseline: 2.2712x; 1.7236x over previous
//
#include <hip/hip_runtime.h>
#include <math.h>

#define N_TOTAL 30000
#define NPER 10000
#define NEDGE 500000
#define NREL 6
#define SLOPE 0.2f
#define MAXDEG 1024   // LDS cache capacity per destination; fallback path if exceeded

typedef __attribute__((ext_vector_type(4))) float f32x4;
typedef __attribute__((ext_vector_type(8))) short s16x8;
typedef __attribute__((ext_vector_type(4))) short s16x4;
typedef unsigned short u16;
typedef unsigned int u32;

__device__ __forceinline__ u16 f2bf(float v) {
  u32 x = __float_as_uint(v);
  u32 r = (x + 0x7fffu + ((x >> 16) & 1u)) >> 16;  // RNE
  return (u16)r;
}
__device__ __forceinline__ float bf2f(u16 u) {
  return __uint_as_float(((u32)u) << 16);
}

// ---------------------------------------------------------------------------
// Split-precision bf16 MFMA GEMM: C[M,128] = A[M,K](f32) @ B[K,128] (+bias)(+ELU)
// A staged as hi/lo bf16 pair -> 2 MFMAs per fragment: ~f32-accurate products,
// only B (weight) rounding remains.
// Tile BM=64, BN=128, BK=64. 256 threads = 4 waves (2x2), wave tile 32x64.
// LDS XOR-swizzled (byte ^= (row&7)<<4) so ds_read_b128 frags are conflict-free.
// C/D frag: col=lane&15, row=(lane>>4)*4+reg  [guide m89/m91 verified].
// ---------------------------------------------------------------------------
struct GB {
  const float* A[6];
  const u16* Bt[6];     // [128][Kp] bf16, transposed, zero-padded to Kp
  const float* bias[6];
  float* C[6];
  int K[6];             // real K (A row stride / bounds)
  int Kp[6];            // padded K (Bt stride, loop bound)
};

template<bool BIAS, bool ELU>
__global__ __launch_bounds__(256, 2)
void gemm_mfma(GB gb, int M)
{
  __shared__ char As[64 * 128];     // hi tile: 64 rows x 64 bf16 (swizzled)
  __shared__ char Aslo[64 * 128];   // lo tile
  __shared__ char Bs[128 * 128];    // 128 n-rows x 64 bf16 (swizzled)
  const int z = blockIdx.z;
  const int K = gb.K[z], Kp = gb.Kp[z];
  const int tid = threadIdx.x;
  const int bm = blockIdx.x * 64;
  const int lane = tid & 63;
  const int wave = tid >> 6;
  const int wr = wave >> 1, wc = wave & 1;
  const int lane16 = lane & 15, lhalf = lane >> 4;
  const float* A = gb.A[z];
  const u16* Bt = gb.Bt[z];

  f32x4 acc[2][4];
  #pragma unroll
  for (int mi = 0; mi < 2; mi++)
    #pragma unroll
    for (int ni = 0; ni < 4; ni++)
      #pragma unroll
      for (int q = 0; q < 4; q++) acc[mi][ni][q] = 0.f;

  for (int k0 = 0; k0 < Kp; k0 += 64) {
    // ---- stage A tile (64 rows x 64 k, f32 -> hi/lo bf16) ----
    #pragma unroll
    for (int it = 0; it < 4; it++) {
      int idx = tid + it * 256;        // 1024 float4 units
      int row = idx >> 4;              // 16 float4 per row
      int kc = (idx & 15) << 2;
      int gr = bm + row, gk = k0 + kc;
      float4 v = make_float4(0.f, 0.f, 0.f, 0.f);
      if (gr < M && gk < K) v = *(const float4*)&A[(size_t)gr * K + gk];
      s16x4 hi, lo;
      float vv[4] = {v.x, v.y, v.z, v.w};
      #pragma unroll
      for (int j = 0; j < 4; j++) {
        u16 h = f2bf(vv[j]);
        hi[j] = (short)h;
        lo[j] = (short)f2bf(vv[j] - bf2f(h));
      }
      int boff = row * 128 + ((kc * 2) ^ ((row & 7) << 4));
      *(s16x4*)(As + boff) = hi;
      *(s16x4*)(Aslo + boff) = lo;
    }
    // ---- stage B tile (128 n-rows x 64 k), Bt zero-padded to Kp ----
    #pragma unroll
    for (int it = 0; it < 4; it++) {
      int idx = tid + it * 256;          // 1024 x 16B chunks
      int row = idx >> 3;
      int kc = (idx & 7) << 3;
      s16x8 v = *(const s16x8*)&Bt[(size_t)row * Kp + k0 + kc];
      *(s16x8*)(Bs + row * 128 + ((kc * 2) ^ ((row & 7) << 4))) = v;
    }
    __syncthreads();
    #pragma unroll
    for (int kk = 0; kk < 2; kk++) {
      const int kbyte = kk * 64 + lhalf * 16;
      s16x8 afh[2], afl[2], bfr[4];
      #pragma unroll
      for (int mi = 0; mi < 2; mi++) {
        int row = wr * 32 + mi * 16 + lane16;
        int boff = row * 128 + (kbyte ^ ((row & 7) << 4));
        afh[mi] = *(const s16x8*)(As + boff);
        afl[mi] = *(const s16x8*)(Aslo + boff);
      }
      #pragma unroll
      for (int ni = 0; ni < 4; ni++) {
        int row = wc * 64 + ni * 16 + lane16;
        bfr[ni] = *(const s16x8*)(Bs + row * 128 + (kbyte ^ ((row & 7) << 4)));
      }
      #pragma unroll
      for (int mi = 0; mi < 2; mi++)
        #pragma unroll
        for (int ni = 0; ni < 4; ni++) {
          acc[mi][ni] = __builtin_amdgcn_mfma_f32_16x16x32_bf16(
              afl[mi], bfr[ni], acc[mi][ni], 0, 0, 0);
          acc[mi][ni] = __builtin_amdgcn_mfma_f32_16x16x32_bf16(
              afh[mi], bfr[ni], acc[mi][ni], 0, 0, 0);
        }
    }
    __syncthreads();
  }

  float bcol[4];
  #pragma unroll
  for (int ni = 0; ni < 4; ni++) {
    int col = wc * 64 + ni * 16 + lane16;
    if (BIAS) bcol[ni] = gb.bias[z][col];
  }
  #pragma unroll
  for (int mi = 0; mi < 2; mi++) {
    #pragma unroll
    for (int q = 0; q < 4; q++) {
      int grow = bm + wr * 32 + mi * 16 + lhalf * 4 + q;
      if (grow < M) {
        #pragma unroll
        for (int ni = 0; ni < 4; ni++) {
          float v = acc[mi][ni][q];
          if (BIAS) v += bcol[ni];
          if (ELU) v = v > 0.f ? v : expm1f(v);
          int col = wc * 64 + ni * 16 + lane16;
          gb.C[z][(size_t)grow * 128 + col] = v;
        }
      }
    }
  }
}

// ---------------------------------------------------------------------------
// Weight convert: src f32 [K][128] -> dst bf16 [128][Kp] (transposed, padded)
// ---------------------------------------------------------------------------
struct CW {
  const float* src[19];
  u16* dst[19];
  int K[19];
  int Kp[19];
};

__global__ __launch_bounds__(256)
void conv_w(CW cw) {
  int z = blockIdx.z;
  int K = cw.K[z], Kp = cw.Kp[z];
  int idx = blockIdx.x * 256 + threadIdx.x;
  if (idx >= 128 * Kp) return;
  int kq = idx >> 7, n = idx & 127;
  cw.dst[z][(size_t)n * Kp + kq] =
      (kq < K) ? f2bf(cw.src[z][(size_t)kq * 128 + n]) : (u16)0;
}

// ---------------------------------------------------------------------------
// Attention-score precompute: Wq[r] = W[r] @ q (exact f32, associativity),
// then QD[r,n] = X[n,:] . Wq[r].
// ---------------------------------------------------------------------------
__global__ __launch_bounds__(128)
void wqk_kernel(const float* __restrict__ W, const float* __restrict__ q,
                const float* __restrict__ k, float* __restrict__ wq,
                float* __restrict__ wk)
{
  int r = blockIdx.x;
  int t = threadIdx.x;
  const float* Wr = W + (size_t)r * 128 * 128 + (size_t)t * 128;
  float aq = 0.f, ak = 0.f;
  for (int o = 0; o < 128; o++) {
    float w = Wr[o];
    aq = fmaf(w, q[o], aq);
    ak = fmaf(w, k[o], ak);
  }
  wq[r * 128 + t] = aq;
  wk[r * 128 + t] = ak;
}

__global__ __launch_bounds__(256)
void qdkd_kernel(const float* __restrict__ Xf, const float* __restrict__ wq,
                 const float* __restrict__ wk, float* __restrict__ QD,
                 float* __restrict__ KD)
{
  __shared__ float sq[NREL * 128], sk[NREL * 128];
  for (int i = threadIdx.x; i < NREL * 128; i += 256) { sq[i] = wq[i]; sk[i] = wk[i]; }
  __syncthreads();
  int n = blockIdx.x * 256 + threadIdx.x;
  if (n >= N_TOTAL) return;
  float aq[NREL], ak[NREL];
  #pragma unroll
  for (int r = 0; r < NREL; r++) { aq[r] = 0.f; ak[r] = 0.f; }
  for (int kc = 0; kc < 128; kc += 4) {
    float4 x = *(const float4*)&Xf[(size_t)n * 128 + kc];
    #pragma unroll
    for (int r = 0; r < NREL; r++) {
      aq[r] += x.x * sq[r * 128 + kc] + x.y * sq[r * 128 + kc + 1]
             + x.z * sq[r * 128 + kc + 2] + x.w * sq[r * 128 + kc + 3];
      ak[r] += x.x * sk[r * 128 + kc] + x.y * sk[r * 128 + kc + 1]
             + x.z * sk[r * 128 + kc + 2] + x.w * sk[r * 128 + kc + 3];
    }
  }
  #pragma unroll
  for (int r = 0; r < NREL; r++) {
    QD[(size_t)r * N_TOTAL + n] = aq[r];
    KD[(size_t)r * N_TOTAL + n] = ak[r];
  }
}

// ---------------------------------------------------------------------------
// CSR build: count -> scan -> fill  (order within a dst group is atomic-
// nondeterministic; only permutes f32 summation order, within noise)
// ---------------------------------------------------------------------------
__global__ __launch_bounds__(256)
void edge_count(const int* __restrict__ dst, int* __restrict__ cnt) {
  int e = blockIdx.x * 256 + threadIdx.x;
  if (e < NEDGE) atomicAdd(&cnt[dst[e]], 1);
}

__global__ __launch_bounds__(1024)
void scan_kernel(const int* __restrict__ cnt, int* __restrict__ off,
                 int* __restrict__ cur) {
  __shared__ int ps[1024];
  const int t = threadIdx.x;
  const int CH = (N_TOTAL + 1023) / 1024;  // 30
  const int base = t * CH;
  int s = 0;
  for (int i = 0; i < CH; i++) {
    int idx = base + i;
    if (idx < N_TOTAL) s += cnt[idx];
  }
  ps[t] = s;
  __syncthreads();
  for (int o = 1; o < 1024; o <<= 1) {
    int v = (t >= o) ? ps[t - o] : 0;
    __syncthreads();
    ps[t] += v;
    __syncthreads();
  }
  int run = ps[t] - s;  // exclusive prefix of this chunk
  for (int i = 0; i < CH; i++) {
    int idx = base + i;
    if (idx < N_TOTAL) {
      off[idx] = run; cur[idx] = run;
      run += cnt[idx];
    }
  }
  if (t == 1023) off[N_TOTAL] = run;
}

__global__ __launch_bounds__(256)
void edge_fill(const int* __restrict__ dst, int* __restrict__ cur,
               int* __restrict__ csre) {
  int e = blockIdx.x * 256 + threadIdx.x;
  if (e >= NEDGE) return;
  int p = atomicAdd(&cur[dst[e]], 1);
  csre[p] = e;
}

// ---------------------------------------------------------------------------
// Fused per-destination attention + aggregation + combine.
// One block (128 threads = 2 waves) per destination node d:
//   phase 1: alpha per edge (cached in LDS), block max
//   phase 2: sum exp(alpha-m); coef = exp(alpha-m)/s*deg
//   phase 3: acc[col] = sum_e coef_e * XW[t_e][src_e][col]  (coalesced rows)
//   write:   h[d] = elu(acc + bias + sl[d])
// ---------------------------------------------------------------------------
__device__ __forceinline__ float block_max2(float v, float* red, int tid) {
  #pragma unroll
  for (int m = 32; m; m >>= 1) v = fmaxf(v, __shfl_xor(v, m));
  if ((tid & 63) == 0) red[tid >> 6] = v;
  __syncthreads();
  return fmaxf(red[0], red[1]);
}
__device__ __forceinline__ float block_sum2(float v, float* red, int tid) {
  #pragma unroll
  for (int m = 32; m; m >>= 1) v += __shfl_xor(v, m);
  if ((tid & 63) == 0) red[tid >> 6] = v;
  __syncthreads();
  return red[0] + red[1];
}

__global__ __launch_bounds__(128)
void csr_agg(const int* __restrict__ off, const int* __restrict__ csre,
             const int* __restrict__ src, const int* __restrict__ et,
             const float* __restrict__ qd, const float* __restrict__ kd,
             const float* __restrict__ xw, const float* __restrict__ sl,
             const float* __restrict__ bias, float* __restrict__ h)
{
  __shared__ float al[MAXDEG];
  __shared__ int2 st[MAXDEG];
  __shared__ float redm[2], reds[2];
  __shared__ float qrow[NREL];
  const int d = blockIdx.x;
  const int tid = threadIdx.x;
  const int n0 = off[d], n1 = off[d + 1];
  const int deg = n1 - n0;
  float acc = 0.f;

  if (deg > 0) {
    if (tid < NREL) qrow[tid] = qd[tid * N_TOTAL + d];
    __syncthreads();
    const bool fits = (deg <= MAXDEG);
    float lmax = -3.0e38f;
    for (int i = tid; i < deg; i += 128) {
      int e = csre[n0 + i];
      int t = et[e], s_ = src[e];
      float a = qrow[t] + kd[t * N_TOTAL + s_];
      a = (a > 0.f) ? a : SLOPE * a;
      if (fits) { al[i] = a; st[i] = make_int2(t, s_); }
      lmax = fmaxf(lmax, a);
    }
    __syncthreads();
    const float m = block_max2(lmax, redm, tid);
    float lsum = 0.f;
    for (int i = tid; i < deg; i += 128) {
      float a;
      if (fits) a = al[i];
      else {
        int e = csre[n0 + i];
        a = qrow[et[e]] + kd[et[e] * N_TOTAL + src[e]];
        a = (a > 0.f) ? a : SLOPE * a;
      }
      lsum += expf(a - m);
    }
    const float ssum = block_sum2(lsum, reds, tid);
    const float scale = (float)deg / ssum;
    if (fits) {
      for (int i = tid; i < deg; i += 128)
        al[i] = expf(al[i] - m) * scale;     // own elements (same striding)
    }
    __syncthreads();
    // ---- weighted gather-accumulate, 2-way unrolled ----
    int i = 0;
    if (fits) {
      for (; i + 1 < deg; i += 2) {
        float c0 = al[i], c1 = al[i + 1];
        int2 e0 = st[i], e1 = st[i + 1];
        float v0 = xw[((size_t)e0.x * N_TOTAL + e0.y) * 128 + tid];
        float v1 = xw[((size_t)e1.x * N_TOTAL + e1.y) * 128 + tid];
        acc = fmaf(c0, v0, acc);
        acc = fmaf(c1, v1, acc);
      }
      if (i < deg) {
        int2 e0 = st[i];
        acc = fmaf(al[i], xw[((size_t)e0.x * N_TOTAL + e0.y) * 128 + tid], acc);
      }
    } else {
      for (i = 0; i < deg; i++) {
        int e = csre[n0 + i];
        int t = et[e], s_ = src[e];
        float a = qrow[t] + kd[t * N_TOTAL + s_];
        a = (a > 0.f) ? a : SLOPE * a;
        float c = expf(a - m) * scale;
        acc = fmaf(c, xw[((size_t)t * N_TOTAL + s_) * 128 + tid], acc);
      }
    }
  }
  float v = acc + bias[tid] + sl[(size_t)d * 128 + tid];
  h[(size_t)d * 128 + tid] = v > 0.f ? v : expm1f(v);
}

__global__ __launch_bounds__(256)
void lin2_kernel(const float* __restrict__ z, const float* __restrict__ W,
                 const float* __restrict__ b, float* __restrict__ out)
{
  int row = blockIdx.x * 4 + (threadIdx.x >> 6);
  int lane = threadIdx.x & 63;
  if (row >= NPER) return;
  float p[5] = {0.f, 0.f, 0.f, 0.f, 0.f};
  #pragma unroll
  for (int h = 0; h < 2; h++) {
    int kidx = lane + h * 64;
    float zv = z[(size_t)row * 128 + kidx];
    #pragma unroll
    for (int j = 0; j < 5; j++) p[j] = fmaf(zv, W[kidx * 5 + j], p[j]);
  }
  #pragma unroll
  for (int mm = 32; mm; mm >>= 1)
    #pragma unroll
    for (int j = 0; j < 5; j++) p[j] += __shfl_xor(p[j], mm);
  if (lane == 0) {
    #pragma unroll
    for (int j = 0; j < 5; j++) out[(size_t)row * 5 + j] = p[j] + b[j];
  }
}

// ---------------------------------------------------------------------------
extern "C" void kernel_launch(void* const* d_in, const int* in_sizes, int n_in,
                              void* d_out, int out_size, void* d_ws, size_t ws_size,
                              hipStream_t stream) {
  const float* xs[3] = {(const float*)d_in[0], (const float*)d_in[1], (const float*)d_in[2]};
  const float* projW[3] = {(const float*)d_in[3], (const float*)d_in[5], (const float*)d_in[7]};
  const float* projb[3] = {(const float*)d_in[4], (const float*)d_in[6], (const float*)d_in[8]};
  const float* slW[3]   = {(const float*)d_in[9], (const float*)d_in[11], (const float*)d_in[13]};
  const float* slb[3]   = {(const float*)d_in[10], (const float*)d_in[12], (const float*)d_in[14]};
  const float* W1 = (const float*)d_in[15];
  const float* q1 = (const float*)d_in[16];
  const float* k1 = (const float*)d_in[17];
  const float* b1 = (const float*)d_in[18];
  const float* W2 = (const float*)d_in[19];
  const float* q2 = (const float*)d_in[20];
  const float* k2 = (const float*)d_in[21];
  const float* b2 = (const float*)d_in[22];
  const float* lin1W = (const float*)d_in[23];
  const float* lin1b = (const float*)d_in[24];
  const float* lin2W = (const float*)d_in[25];
  const float* lin2b = (const float*)d_in[26];
  const int* esrc = (const int*)d_in[27];
  const int* edst = (const int*)d_in[28];
  const int* etyp = (const int*)d_in[29];

  char* wp = (char*)d_ws;
  auto alloc = [&](size_t bytes) -> char* {
    char* p = wp; wp += (bytes + 255) & ~(size_t)255; return p;
  };
  float* Xf  = (float*)alloc((size_t)N_TOTAL * 128 * 4);
  float* SL  = (float*)alloc((size_t)N_TOTAL * 128 * 4);
  float* Hf  = (float*)alloc((size_t)N_TOTAL * 128 * 4);
  float* QD  = (float*)alloc((size_t)NREL * N_TOTAL * 4);
  float* KD  = (float*)alloc((size_t)NREL * N_TOTAL * 4);
  float* Z   = (float*)alloc((size_t)NPER * 128 * 4);
  float* WQ1 = (float*)alloc((size_t)NREL * 128 * 4);
  float* WK1 = (float*)alloc((size_t)NREL * 128 * 4);
  float* WQ2 = (float*)alloc((size_t)NREL * 128 * 4);
  float* WK2 = (float*)alloc((size_t)NREL * 128 * 4);
  int*   CNT = (int*)  alloc((size_t)N_TOTAL * 4);
  int*   OFF = (int*)  alloc((size_t)(N_TOTAL + 1) * 4);
  int*   CUR = (int*)  alloc((size_t)N_TOTAL * 4);
  int*   CSRE= (int*)  alloc((size_t)NEDGE * 4);

  // ---- weight conversion table (transposed + K padded to 64) ----
  CW cw;
  int nW = 0;
  auto addW = [&](const float* src, int K) {
    int Kp = (K + 63) & ~63;
    cw.src[nW] = src; cw.K[nW] = K; cw.Kp[nW] = Kp;
    cw.dst[nW] = (u16*)alloc((size_t)128 * Kp * 2);
    nW++;
  };
  addW(projW[0], 2000); addW(projW[1], 1500); addW(projW[2], 1000);
  addW(slW[0], 128); addW(slW[1], 128); addW(slW[2], 128);
  for (int r = 0; r < NREL; r++) addW(W1 + (size_t)r * 128 * 128, 128);
  for (int r = 0; r < NREL; r++) addW(W2 + (size_t)r * 128 * 128, 128);
  addW(lin1W, 128);   // nW == 19

  float* XW = (float*)alloc((size_t)NREL * N_TOTAL * 128 * 4);  // 92 MB

  const int gridM_per = (NPER + 63) / 64;     // 157
  const int gridM_tot = (N_TOTAL + 63) / 64;  // 469
  const int gridE = (NEDGE + 255) / 256;
  const int gridN = (N_TOTAL + 255) / 256;

  // ---- CSR build (edge-list only; shared by both layers) ----
  hipMemsetAsync(CNT, 0, (size_t)N_TOTAL * 4, stream);
  edge_count<<<gridE, 256, 0, stream>>>(edst, CNT);
  scan_kernel<<<1, 1024, 0, stream>>>(CNT, OFF, CUR);
  edge_fill<<<gridE, 256, 0, stream>>>(edst, CUR, CSRE);

  conv_w<<<dim3(1024, 1, 19), 256, 0, stream>>>(cw);
  wqk_kernel<<<NREL, 128, 0, stream>>>(W1, q1, k1, WQ1, WK1);
  wqk_kernel<<<NREL, 128, 0, stream>>>(W2, q2, k2, WQ2, WK2);

  // ---- projections: Xf = elu(x_i @ projW_i + projb_i) ----
  {
    GB g;
    for (int z = 0; z < 3; z++) {
      g.A[z] = xs[z]; g.Bt[z] = cw.dst[z]; g.bias[z] = projb[z];
      g.C[z] = Xf + (size_t)z * NPER * 128;
      g.K[z] = cw.K[z]; g.Kp[z] = cw.Kp[z];
    }
    gemm_mfma<true, true><<<dim3(gridM_per, 1, 3), 256, 0, stream>>>(g, NPER);
  }
  // ---- self-loops: SL = Xf_i @ slW_i + slb_i ----
  {
    GB g;
    for (int z = 0; z < 3; z++) {
      g.A[z] = Xf + (size_t)z * NPER * 128; g.Bt[z] = cw.dst[3 + z];
      g.bias[z] = slb[z]; g.C[z] = SL + (size_t)z * NPER * 128;
      g.K[z] = 128; g.Kp[z] = 128;
    }
    gemm_mfma<true, false><<<dim3(gridM_per, 1, 3), 256, 0, stream>>>(g, NPER);
  }

  for (int layer = 0; layer < 2; layer++) {
    const float* Ain = (layer == 0) ? Xf : Hf;
    const float* WQ = (layer == 0) ? WQ1 : WQ2;
    const float* WK = (layer == 0) ? WK1 : WK2;
    const float* bb = (layer == 0) ? b1 : b2;
    int wbase = (layer == 0) ? 6 : 12;

    qdkd_kernel<<<gridN, 256, 0, stream>>>(Ain, WQ, WK, QD, KD);
    {
      GB g;
      for (int z = 0; z < NREL; z++) {
        g.A[z] = Ain; g.Bt[z] = cw.dst[wbase + z]; g.bias[z] = nullptr;
        g.C[z] = XW + (size_t)z * N_TOTAL * 128;
        g.K[z] = 128; g.Kp[z] = 128;
      }
      gemm_mfma<false, false><<<dim3(gridM_tot, 1, NREL), 256, 0, stream>>>(g, N_TOTAL);
    }
    csr_agg<<<N_TOTAL, 128, 0, stream>>>(OFF, CSRE, esrc, etyp, QD, KD, XW, SL, bb, Hf);
  }

  // ---- head ----
  {
    GB g;
    g.A[0] = Hf; g.Bt[0] = cw.dst[18]; g.bias[0] = lin1b; g.C[0] = Z;
    g.K[0] = 128; g.Kp[0] = 128;
    gemm_mfma<true, true><<<dim3(gridM_per, 1, 1), 256, 0, stream>>>(g, NPER);
  }
  lin2_kernel<<<(NPER + 3) / 4, 256, 0, stream>>>(Z, lin2W, lin2b, (float*)d_out);
}

// Round 5
// 501.854 us; speedup vs baseline: 2.3248x; 1.0236x over previous
//
#include <hip/hip_runtime.h>
#include <math.h>

#define N_TOTAL 30000
#define NPER 10000
#define NEDGE 500000
#define NREL 6
#define SLOPE 0.2f
#define MAXDEG 256    // LDS cache per destination; recompute fallback if exceeded

typedef __attribute__((ext_vector_type(4))) float f32x4;
typedef __attribute__((ext_vector_type(8))) short s16x8;
typedef __attribute__((ext_vector_type(4))) short s16x4;
typedef unsigned short u16;
typedef unsigned int u32;

__device__ __forceinline__ u16 f2bf(float v) {
  u32 x = __float_as_uint(v);
  u32 r = (x + 0x7fffu + ((x >> 16) & 1u)) >> 16;  // RNE
  return (u16)r;
}
__device__ __forceinline__ float bf2f(u16 u) {
  return __uint_as_float(((u32)u) << 16);
}

// ---------------------------------------------------------------------------
// Split-precision bf16 MFMA GEMM: C[M,128] = A[M,K](f32) @ B[K,128]
// (+bias)(+ADD row)(+ELU). A staged as hi/lo bf16 -> 2 MFMAs per fragment.
// Tile BM=64, BN=128, BK=64. 256 thr = 4 waves (2x2), wave tile 32x64.
// LDS XOR-swizzle (byte ^= (row&7)<<4); C/D: col=lane&15, row=(lane>>4)*4+reg.
// ---------------------------------------------------------------------------
struct GB {
  const float* A[3];
  const u16* Bt[3];     // [128][Kp] bf16, transposed, zero-padded
  const float* bias[3];
  const float* add[3];  // optional row-major [M][128] addend (SL)
  float* C[3];
  int K[3];
  int Kp[3];
};

template<bool BIAS, bool ELU, bool ADD>
__global__ __launch_bounds__(256, 2)
void gemm_mfma(GB gb, int M)
{
  __shared__ char As[64 * 128];
  __shared__ char Aslo[64 * 128];
  __shared__ char Bs[128 * 128];
  const int z = blockIdx.z;
  const int K = gb.K[z], Kp = gb.Kp[z];
  const int tid = threadIdx.x;
  const int bm = blockIdx.x * 64;
  const int lane = tid & 63;
  const int wave = tid >> 6;
  const int wr = wave >> 1, wc = wave & 1;
  const int lane16 = lane & 15, lhalf = lane >> 4;
  const float* A = gb.A[z];
  const u16* Bt = gb.Bt[z];

  f32x4 acc[2][4];
  #pragma unroll
  for (int mi = 0; mi < 2; mi++)
    #pragma unroll
    for (int ni = 0; ni < 4; ni++)
      #pragma unroll
      for (int q = 0; q < 4; q++) acc[mi][ni][q] = 0.f;

  for (int k0 = 0; k0 < Kp; k0 += 64) {
    #pragma unroll
    for (int it = 0; it < 4; it++) {
      int idx = tid + it * 256;
      int row = idx >> 4;
      int kc = (idx & 15) << 2;
      int gr = bm + row, gk = k0 + kc;
      float4 v = make_float4(0.f, 0.f, 0.f, 0.f);
      if (gr < M && gk < K) v = *(const float4*)&A[(size_t)gr * K + gk];
      s16x4 hi, lo;
      float vv[4] = {v.x, v.y, v.z, v.w};
      #pragma unroll
      for (int j = 0; j < 4; j++) {
        u16 h = f2bf(vv[j]);
        hi[j] = (short)h;
        lo[j] = (short)f2bf(vv[j] - bf2f(h));
      }
      int boff = row * 128 + ((kc * 2) ^ ((row & 7) << 4));
      *(s16x4*)(As + boff) = hi;
      *(s16x4*)(Aslo + boff) = lo;
    }
    #pragma unroll
    for (int it = 0; it < 4; it++) {
      int idx = tid + it * 256;
      int row = idx >> 3;
      int kc = (idx & 7) << 3;
      s16x8 v = *(const s16x8*)&Bt[(size_t)row * Kp + k0 + kc];
      *(s16x8*)(Bs + row * 128 + ((kc * 2) ^ ((row & 7) << 4))) = v;
    }
    __syncthreads();
    #pragma unroll
    for (int kk = 0; kk < 2; kk++) {
      const int kbyte = kk * 64 + lhalf * 16;
      s16x8 afh[2], afl[2], bfr[4];
      #pragma unroll
      for (int mi = 0; mi < 2; mi++) {
        int row = wr * 32 + mi * 16 + lane16;
        int boff = row * 128 + (kbyte ^ ((row & 7) << 4));
        afh[mi] = *(const s16x8*)(As + boff);
        afl[mi] = *(const s16x8*)(Aslo + boff);
      }
      #pragma unroll
      for (int ni = 0; ni < 4; ni++) {
        int row = wc * 64 + ni * 16 + lane16;
        bfr[ni] = *(const s16x8*)(Bs + row * 128 + (kbyte ^ ((row & 7) << 4)));
      }
      #pragma unroll
      for (int mi = 0; mi < 2; mi++)
        #pragma unroll
        for (int ni = 0; ni < 4; ni++) {
          acc[mi][ni] = __builtin_amdgcn_mfma_f32_16x16x32_bf16(
              afl[mi], bfr[ni], acc[mi][ni], 0, 0, 0);
          acc[mi][ni] = __builtin_amdgcn_mfma_f32_16x16x32_bf16(
              afh[mi], bfr[ni], acc[mi][ni], 0, 0, 0);
        }
    }
    __syncthreads();
  }

  float bcol[4];
  #pragma unroll
  for (int ni = 0; ni < 4; ni++) {
    int col = wc * 64 + ni * 16 + lane16;
    if (BIAS) bcol[ni] = gb.bias[z][col];
  }
  #pragma unroll
  for (int mi = 0; mi < 2; mi++) {
    #pragma unroll
    for (int q = 0; q < 4; q++) {
      int grow = bm + wr * 32 + mi * 16 + lhalf * 4 + q;
      if (grow < M) {
        #pragma unroll
        for (int ni = 0; ni < 4; ni++) {
          float v = acc[mi][ni][q];
          int col = wc * 64 + ni * 16 + lane16;
          if (BIAS) v += bcol[ni];
          if (ADD) v += gb.add[z][(size_t)grow * 128 + col];
          if (ELU) v = v > 0.f ? v : expm1f(v);
          gb.C[z][(size_t)grow * 128 + col] = v;
        }
      }
    }
  }
}

// ---------------------------------------------------------------------------
// Split-K projection GEMM: chunk = 512 K (8 steps). Writes raw f32 partials to
// PART[z][chunk][M][128]. grid (157, 4, 3); idle chunks exit.
// ---------------------------------------------------------------------------
struct SK {
  const float* A[3];
  const u16* Bt[3];
  float* C[3];          // PART base per omic: + chunk*M*128
  int K[3];
  int Kp[3];
};

__global__ __launch_bounds__(256, 2)
void gemm_splitk(SK sk, int M)
{
  __shared__ char As[64 * 128];
  __shared__ char Aslo[64 * 128];
  __shared__ char Bs[128 * 128];
  const int z = blockIdx.z;
  const int K = sk.K[z], Kp = sk.Kp[z];
  const int cb = blockIdx.y * 512;
  if (cb >= Kp) return;
  const int kend = (cb + 512 < Kp) ? cb + 512 : Kp;
  const int tid = threadIdx.x;
  const int bm = blockIdx.x * 64;
  const int lane = tid & 63;
  const int wave = tid >> 6;
  const int wr = wave >> 1, wc = wave & 1;
  const int lane16 = lane & 15, lhalf = lane >> 4;
  const float* A = sk.A[z];
  const u16* Bt = sk.Bt[z];

  f32x4 acc[2][4];
  #pragma unroll
  for (int mi = 0; mi < 2; mi++)
    #pragma unroll
    for (int ni = 0; ni < 4; ni++)
      #pragma unroll
      for (int q = 0; q < 4; q++) acc[mi][ni][q] = 0.f;

  for (int k0 = cb; k0 < kend; k0 += 64) {
    #pragma unroll
    for (int it = 0; it < 4; it++) {
      int idx = tid + it * 256;
      int row = idx >> 4;
      int kc = (idx & 15) << 2;
      int gr = bm + row, gk = k0 + kc;
      float4 v = make_float4(0.f, 0.f, 0.f, 0.f);
      if (gr < M && gk < K) v = *(const float4*)&A[(size_t)gr * K + gk];
      s16x4 hi, lo;
      float vv[4] = {v.x, v.y, v.z, v.w};
      #pragma unroll
      for (int j = 0; j < 4; j++) {
        u16 h = f2bf(vv[j]);
        hi[j] = (short)h;
        lo[j] = (short)f2bf(vv[j] - bf2f(h));
      }
      int boff = row * 128 + ((kc * 2) ^ ((row & 7) << 4));
      *(s16x4*)(As + boff) = hi;
      *(s16x4*)(Aslo + boff) = lo;
    }
    #pragma unroll
    for (int it = 0; it < 4; it++) {
      int idx = tid + it * 256;
      int row = idx >> 3;
      int kc = (idx & 7) << 3;
      s16x8 v = *(const s16x8*)&Bt[(size_t)row * Kp + k0 + kc];
      *(s16x8*)(Bs + row * 128 + ((kc * 2) ^ ((row & 7) << 4))) = v;
    }
    __syncthreads();
    #pragma unroll
    for (int kk = 0; kk < 2; kk++) {
      const int kbyte = kk * 64 + lhalf * 16;
      s16x8 afh[2], afl[2], bfr[4];
      #pragma unroll
      for (int mi = 0; mi < 2; mi++) {
        int row = wr * 32 + mi * 16 + lane16;
        int boff = row * 128 + (kbyte ^ ((row & 7) << 4));
        afh[mi] = *(const s16x8*)(As + boff);
        afl[mi] = *(const s16x8*)(Aslo + boff);
      }
      #pragma unroll
      for (int ni = 0; ni < 4; ni++) {
        int row = wc * 64 + ni * 16 + lane16;
        bfr[ni] = *(const s16x8*)(Bs + row * 128 + (kbyte ^ ((row & 7) << 4)));
      }
      #pragma unroll
      for (int mi = 0; mi < 2; mi++)
        #pragma unroll
        for (int ni = 0; ni < 4; ni++) {
          acc[mi][ni] = __builtin_amdgcn_mfma_f32_16x16x32_bf16(
              afl[mi], bfr[ni], acc[mi][ni], 0, 0, 0);
          acc[mi][ni] = __builtin_amdgcn_mfma_f32_16x16x32_bf16(
              afh[mi], bfr[ni], acc[mi][ni], 0, 0, 0);
        }
    }
    __syncthreads();
  }

  float* C = sk.C[z] + (size_t)blockIdx.y * M * 128;
  #pragma unroll
  for (int mi = 0; mi < 2; mi++) {
    #pragma unroll
    for (int q = 0; q < 4; q++) {
      int grow = bm + wr * 32 + mi * 16 + lhalf * 4 + q;
      if (grow < M) {
        #pragma unroll
        for (int ni = 0; ni < 4; ni++) {
          int col = wc * 64 + ni * 16 + lane16;
          C[(size_t)grow * 128 + col] = acc[mi][ni][q];
        }
      }
    }
  }
}

struct RP { const float* bias[3]; int nch[3]; };

__global__ __launch_bounds__(256)
void reduce_proj(const float* __restrict__ part, RP rp, float* __restrict__ Xf)
{
  int z = blockIdx.z;
  int i = blockIdx.x * 256 + threadIdx.x;   // over NPER*128
  int c = i & 127;
  int nch = rp.nch[z];
  const float* base = part + (size_t)z * 4 * NPER * 128 + i;
  float s = 0.f;
  for (int ch = 0; ch < nch; ch++) s += base[(size_t)ch * NPER * 128];
  s += rp.bias[z][c];
  Xf[(size_t)z * NPER * 128 + i] = s > 0.f ? s : expm1f(s);
}

// ---------------------------------------------------------------------------
// Weight convert: src f32 [K][128] -> dst bf16 [128][Kp] (transposed, padded)
// ---------------------------------------------------------------------------
struct CW {
  const float* src[9];
  u16* dst[9];
  int K[9];
  int Kp[9];
};

__global__ __launch_bounds__(256)
void conv_w(CW cw) {
  int z = blockIdx.z;
  int K = cw.K[z], Kp = cw.Kp[z];
  int idx = blockIdx.x * 256 + threadIdx.x;
  if (idx >= 128 * Kp) return;
  int kq = idx >> 7, n = idx & 127;
  cw.dst[z][(size_t)n * Kp + kq] =
      (kq < K) ? f2bf(cw.src[z][(size_t)kq * 128 + n]) : (u16)0;
}

// ---------------------------------------------------------------------------
// Attention-score precompute (exact f32): Wq[r]=W[r]@q; QD[r,n]=X[n,:].Wq[r]
// ---------------------------------------------------------------------------
__global__ __launch_bounds__(128)
void wqk_kernel(const float* __restrict__ W, const float* __restrict__ q,
                const float* __restrict__ k, float* __restrict__ wq,
                float* __restrict__ wk)
{
  int r = blockIdx.x;
  int t = threadIdx.x;
  const float* Wr = W + (size_t)r * 128 * 128 + (size_t)t * 128;
  float aq = 0.f, ak = 0.f;
  for (int o = 0; o < 128; o++) {
    float w = Wr[o];
    aq = fmaf(w, q[o], aq);
    ak = fmaf(w, k[o], ak);
  }
  wq[r * 128 + t] = aq;
  wk[r * 128 + t] = ak;
}

__global__ __launch_bounds__(256)
void qdkd_kernel(const float* __restrict__ Xf, const float* __restrict__ wq,
                 const float* __restrict__ wk, float* __restrict__ QD,
                 float* __restrict__ KD)
{
  __shared__ float sq[NREL * 128], sk[NREL * 128];
  for (int i = threadIdx.x; i < NREL * 128; i += 256) { sq[i] = wq[i]; sk[i] = wk[i]; }
  __syncthreads();
  int n = blockIdx.x * 256 + threadIdx.x;
  if (n >= N_TOTAL) return;
  float aq[NREL], ak[NREL];
  #pragma unroll
  for (int r = 0; r < NREL; r++) { aq[r] = 0.f; ak[r] = 0.f; }
  for (int kc = 0; kc < 128; kc += 4) {
    float4 x = *(const float4*)&Xf[(size_t)n * 128 + kc];
    #pragma unroll
    for (int r = 0; r < NREL; r++) {
      aq[r] += x.x * sq[r * 128 + kc] + x.y * sq[r * 128 + kc + 1]
             + x.z * sq[r * 128 + kc + 2] + x.w * sq[r * 128 + kc + 3];
      ak[r] += x.x * sk[r * 128 + kc] + x.y * sk[r * 128 + kc + 1]
             + x.z * sk[r * 128 + kc + 2] + x.w * sk[r * 128 + kc + 3];
    }
  }
  #pragma unroll
  for (int r = 0; r < NREL; r++) {
    QD[(size_t)r * N_TOTAL + n] = aq[r];
    KD[(size_t)r * N_TOTAL + n] = ak[r];
  }
}

// ---------------------------------------------------------------------------
// CSR build
// ---------------------------------------------------------------------------
__global__ __launch_bounds__(256)
void edge_count(const int* __restrict__ dst, int* __restrict__ cnt) {
  int e = blockIdx.x * 256 + threadIdx.x;
  if (e < NEDGE) atomicAdd(&cnt[dst[e]], 1);
}

__global__ __launch_bounds__(1024)
void scan_kernel(const int* __restrict__ cnt, int* __restrict__ off,
                 int* __restrict__ cur) {
  __shared__ int ps[1024];
  const int t = threadIdx.x;
  const int CH = (N_TOTAL + 1023) / 1024;
  const int base = t * CH;
  int s = 0;
  for (int i = 0; i < CH; i++) {
    int idx = base + i;
    if (idx < N_TOTAL) s += cnt[idx];
  }
  ps[t] = s;
  __syncthreads();
  for (int o = 1; o < 1024; o <<= 1) {
    int v = (t >= o) ? ps[t - o] : 0;
    __syncthreads();
    ps[t] += v;
    __syncthreads();
  }
  int run = ps[t] - s;
  for (int i = 0; i < CH; i++) {
    int idx = base + i;
    if (idx < N_TOTAL) {
      off[idx] = run; cur[idx] = run;
      run += cnt[idx];
    }
  }
  if (t == 1023) off[N_TOTAL] = run;
}

__global__ __launch_bounds__(256)
void edge_fill(const int* __restrict__ dst, int* __restrict__ cur,
               int* __restrict__ csre) {
  int e = blockIdx.x * 256 + threadIdx.x;
  if (e >= NEDGE) return;
  int p = atomicAdd(&cur[dst[e]], 1);
  csre[p] = e;
}

// ---------------------------------------------------------------------------
// Fused per-destination attention + PER-RELATION aggregation in PROJ space.
// Writes AGG[d][r][128] = sum over edges of relation r of coef * x_src.
// Gather table is the hot 15 MB Xf/Hf (not the 92 MB XW).
// ---------------------------------------------------------------------------
__device__ __forceinline__ float block_max2(float v, float* red, int tid) {
  #pragma unroll
  for (int m = 32; m; m >>= 1) v = fmaxf(v, __shfl_xor(v, m));
  if ((tid & 63) == 0) red[tid >> 6] = v;
  __syncthreads();
  return fmaxf(red[0], red[1]);
}
__device__ __forceinline__ float block_sum2(float v, float* red, int tid) {
  #pragma unroll
  for (int m = 32; m; m >>= 1) v += __shfl_xor(v, m);
  if ((tid & 63) == 0) red[tid >> 6] = v;
  __syncthreads();
  return red[0] + red[1];
}

__global__ __launch_bounds__(128)
void csr_agg2(const int* __restrict__ off, const int* __restrict__ csre,
              const int* __restrict__ src, const int* __restrict__ et,
              const float* __restrict__ qd, const float* __restrict__ kd,
              const float* __restrict__ xrow, float* __restrict__ agg)
{
  __shared__ float al[MAXDEG];
  __shared__ int2 st[MAXDEG];
  __shared__ float redm[2], reds[2];
  __shared__ float qrow[NREL];
  const int d = blockIdx.x;
  const int tid = threadIdx.x;
  const int n0 = off[d];
  const int deg = off[d + 1] - n0;
  float accr[NREL] = {0.f, 0.f, 0.f, 0.f, 0.f, 0.f};

  if (deg > 0) {
    if (tid < NREL) qrow[tid] = qd[tid * N_TOTAL + d];
    __syncthreads();
    const bool fits = (deg <= MAXDEG);
    float lmax = -3.0e38f;
    for (int i = tid; i < deg; i += 128) {
      int e = csre[n0 + i];
      int t = et[e], s_ = src[e];
      float a = qrow[t] + kd[t * N_TOTAL + s_];
      a = (a > 0.f) ? a : SLOPE * a;
      if (fits) { al[i] = a; st[i] = make_int2(t, s_); }
      lmax = fmaxf(lmax, a);
    }
    __syncthreads();
    const float m = block_max2(lmax, redm, tid);
    float lsum = 0.f;
    for (int i = tid; i < deg; i += 128) {
      float a;
      if (fits) a = al[i];
      else {
        int e = csre[n0 + i];
        a = qrow[et[e]] + kd[et[e] * N_TOTAL + src[e]];
        a = (a > 0.f) ? a : SLOPE * a;
      }
      lsum += expf(a - m);
    }
    const float ssum = block_sum2(lsum, reds, tid);
    const float scale = (float)deg / ssum;
    if (fits) {
      for (int i = tid; i < deg; i += 128)
        al[i] = expf(al[i] - m) * scale;
    }
    __syncthreads();
    if (fits) {
      int i = 0;
      for (; i + 1 < deg; i += 2) {
        float c0 = al[i], c1 = al[i + 1];
        int2 e0 = st[i], e1 = st[i + 1];
        float v0 = xrow[(size_t)e0.y * 128 + tid];
        float v1 = xrow[(size_t)e1.y * 128 + tid];
        float cv0 = c0 * v0, cv1 = c1 * v1;
        #pragma unroll
        for (int r = 0; r < NREL; r++) {
          accr[r] += (e0.x == r) ? cv0 : 0.f;
          accr[r] += (e1.x == r) ? cv1 : 0.f;
        }
      }
      if (i < deg) {
        int2 e0 = st[i];
        float cv0 = al[i] * xrow[(size_t)e0.y * 128 + tid];
        #pragma unroll
        for (int r = 0; r < NREL; r++) accr[r] += (e0.x == r) ? cv0 : 0.f;
      }
    } else {
      for (int i = 0; i < deg; i++) {
        int e = csre[n0 + i];
        int t = et[e], s_ = src[e];
        float a = qrow[t] + kd[t * N_TOTAL + s_];
        a = (a > 0.f) ? a : SLOPE * a;
        float cv = expf(a - m) * scale * xrow[(size_t)s_ * 128 + tid];
        #pragma unroll
        for (int r = 0; r < NREL; r++) accr[r] += (t == r) ? cv : 0.f;
      }
    }
  }
  #pragma unroll
  for (int r = 0; r < NREL; r++)
    agg[((size_t)d * NREL + r) * 128 + tid] = accr[r];
}

__global__ __launch_bounds__(256)
void lin2_kernel(const float* __restrict__ z, const float* __restrict__ W,
                 const float* __restrict__ b, float* __restrict__ out)
{
  int row = blockIdx.x * 4 + (threadIdx.x >> 6);
  int lane = threadIdx.x & 63;
  if (row >= NPER) return;
  float p[5] = {0.f, 0.f, 0.f, 0.f, 0.f};
  #pragma unroll
  for (int h = 0; h < 2; h++) {
    int kidx = lane + h * 64;
    float zv = z[(size_t)row * 128 + kidx];
    #pragma unroll
    for (int j = 0; j < 5; j++) p[j] = fmaf(zv, W[kidx * 5 + j], p[j]);
  }
  #pragma unroll
  for (int mm = 32; mm; mm >>= 1)
    #pragma unroll
    for (int j = 0; j < 5; j++) p[j] += __shfl_xor(p[j], mm);
  if (lane == 0) {
    #pragma unroll
    for (int j = 0; j < 5; j++) out[(size_t)row * 5 + j] = p[j] + b[j];
  }
}

// ---------------------------------------------------------------------------
extern "C" void kernel_launch(void* const* d_in, const int* in_sizes, int n_in,
                              void* d_out, int out_size, void* d_ws, size_t ws_size,
                              hipStream_t stream) {
  const float* xs[3] = {(const float*)d_in[0], (const float*)d_in[1], (const float*)d_in[2]};
  const float* projW[3] = {(const float*)d_in[3], (const float*)d_in[5], (const float*)d_in[7]};
  const float* projb[3] = {(const float*)d_in[4], (const float*)d_in[6], (const float*)d_in[8]};
  const float* slW[3]   = {(const float*)d_in[9], (const float*)d_in[11], (const float*)d_in[13]};
  const float* slb[3]   = {(const float*)d_in[10], (const float*)d_in[12], (const float*)d_in[14]};
  const float* W1 = (const float*)d_in[15];
  const float* q1 = (const float*)d_in[16];
  const float* k1 = (const float*)d_in[17];
  const float* b1 = (const float*)d_in[18];
  const float* W2 = (const float*)d_in[19];
  const float* q2 = (const float*)d_in[20];
  const float* k2 = (const float*)d_in[21];
  const float* b2 = (const float*)d_in[22];
  const float* lin1W = (const float*)d_in[23];
  const float* lin1b = (const float*)d_in[24];
  const float* lin2W = (const float*)d_in[25];
  const float* lin2b = (const float*)d_in[26];
  const int* esrc = (const int*)d_in[27];
  const int* edst = (const int*)d_in[28];
  const int* etyp = (const int*)d_in[29];

  char* wp = (char*)d_ws;
  auto alloc = [&](size_t bytes) -> char* {
    char* p = wp; wp += (bytes + 255) & ~(size_t)255; return p;
  };
  float* Xf  = (float*)alloc((size_t)N_TOTAL * 128 * 4);
  float* SL  = (float*)alloc((size_t)N_TOTAL * 128 * 4);
  float* Hf  = (float*)alloc((size_t)N_TOTAL * 128 * 4);
  float* QD  = (float*)alloc((size_t)NREL * N_TOTAL * 4);
  float* KD  = (float*)alloc((size_t)NREL * N_TOTAL * 4);
  float* Z   = (float*)alloc((size_t)NPER * 128 * 4);
  float* WQ1 = (float*)alloc((size_t)NREL * 128 * 4);
  float* WK1 = (float*)alloc((size_t)NREL * 128 * 4);
  float* WQ2 = (float*)alloc((size_t)NREL * 128 * 4);
  float* WK2 = (float*)alloc((size_t)NREL * 128 * 4);
  int*   CNT = (int*)  alloc((size_t)N_TOTAL * 4);
  int*   OFF = (int*)  alloc((size_t)(N_TOTAL + 1) * 4);
  int*   CUR = (int*)  alloc((size_t)N_TOTAL * 4);
  int*   CSRE= (int*)  alloc((size_t)NEDGE * 4);

  // AGG [30000][768] f32 (92 MB); its region doubles as split-K PART
  // [3][4][NPER][128] f32 (61 MB) — PART is dead before csr_agg2 runs.
  float* AGG  = (float*)alloc((size_t)N_TOTAL * NREL * 128 * 4);
  float* PART = AGG;

  // ---- weight conversion table (transposed + K padded) ----
  CW cw;
  int nW = 0;
  auto addW = [&](const float* src, int K) {
    int Kp = (K + 63) & ~63;
    cw.src[nW] = src; cw.K[nW] = K; cw.Kp[nW] = Kp;
    cw.dst[nW] = (u16*)alloc((size_t)128 * Kp * 2);
    nW++;
  };
  addW(projW[0], 2000); addW(projW[1], 1500); addW(projW[2], 1000);  // 0-2
  addW(slW[0], 128); addW(slW[1], 128); addW(slW[2], 128);           // 3-5
  addW(W1, NREL * 128);   // 6: stacked [768][128] -> Bt [128][768]
  addW(W2, NREL * 128);   // 7
  addW(lin1W, 128);       // 8

  const int gridM_per = (NPER + 63) / 64;     // 157
  const int gridM_tot = (N_TOTAL + 63) / 64;  // 469
  const int gridE = (NEDGE + 255) / 256;

  // ---- CSR build ----
  hipMemsetAsync(CNT, 0, (size_t)N_TOTAL * 4, stream);
  edge_count<<<gridE, 256, 0, stream>>>(edst, CNT);
  scan_kernel<<<1, 1024, 0, stream>>>(CNT, OFF, CUR);
  edge_fill<<<gridE, 256, 0, stream>>>(edst, CUR, CSRE);

  conv_w<<<dim3(1024, 1, 9), 256, 0, stream>>>(cw);
  wqk_kernel<<<NREL, 128, 0, stream>>>(W1, q1, k1, WQ1, WK1);
  wqk_kernel<<<NREL, 128, 0, stream>>>(W2, q2, k2, WQ2, WK2);

  // ---- projections via split-K (chunks of 512) ----
  {
    SK sk;
    for (int z = 0; z < 3; z++) {
      sk.A[z] = xs[z]; sk.Bt[z] = cw.dst[z];
      sk.C[z] = PART + (size_t)z * 4 * NPER * 128;
      sk.K[z] = cw.K[z]; sk.Kp[z] = cw.Kp[z];
    }
    gemm_splitk<<<dim3(gridM_per, 4, 3), 256, 0, stream>>>(sk, NPER);
    RP rp;
    for (int z = 0; z < 3; z++) { rp.bias[z] = projb[z]; rp.nch[z] = cw.Kp[z] / 512; }
    reduce_proj<<<dim3(NPER * 128 / 256, 1, 3), 256, 0, stream>>>(PART, rp, Xf);
  }
  // ---- self-loops: SL = Xf_i @ slW_i + slb_i ----
  {
    GB g;
    for (int z = 0; z < 3; z++) {
      g.A[z] = Xf + (size_t)z * NPER * 128; g.Bt[z] = cw.dst[3 + z];
      g.bias[z] = slb[z]; g.add[z] = nullptr;
      g.C[z] = SL + (size_t)z * NPER * 128;
      g.K[z] = 128; g.Kp[z] = 128;
    }
    gemm_mfma<true, false, false><<<dim3(gridM_per, 1, 3), 256, 0, stream>>>(g, NPER);
  }

  for (int layer = 0; layer < 2; layer++) {
    const float* Ain = (layer == 0) ? Xf : Hf;
    const float* WQ = (layer == 0) ? WQ1 : WQ2;
    const float* WK = (layer == 0) ? WK1 : WK2;
    const float* bb = (layer == 0) ? b1 : b2;
    const u16* Wstk = cw.dst[6 + layer];

    qdkd_kernel<<<(N_TOTAL + 255) / 256, 256, 0, stream>>>(Ain, WQ, WK, QD, KD);
    csr_agg2<<<N_TOTAL, 128, 0, stream>>>(OFF, CSRE, esrc, etyp, QD, KD, Ain, AGG);
    // transform: Hf = elu(AGG[30000,768] @ Wstack[768,128] + b + SL)
    GB g;
    g.A[0] = AGG; g.Bt[0] = Wstk; g.bias[0] = bb; g.add[0] = SL; g.C[0] = Hf;
    g.K[0] = NREL * 128; g.Kp[0] = NREL * 128;
    gemm_mfma<true, true, true><<<dim3(gridM_tot, 1, 1), 256, 0, stream>>>(g, N_TOTAL);
  }

  // ---- head ----
  {
    GB g;
    g.A[0] = Hf; g.Bt[0] = cw.dst[8]; g.bias[0] = lin1b; g.add[0] = nullptr; g.C[0] = Z;
    g.K[0] = 128; g.Kp[0] = 128;
    gemm_mfma<true, true, false><<<dim3(gridM_per, 1, 1), 256, 0, stream>>>(g, NPER);
  }
  lin2_kernel<<<(NPER + 3) / 4, 256, 0, stream>>>(Z, lin2W, lin2b, (float*)d_out);
}

// Round 6
// 432.896 us; speedup vs baseline: 2.6951x; 1.1593x over previous
//
#include <hip/hip_runtime.h>
#include <math.h>

#define N_TOTAL 30000
#define NPER 10000
#define NEDGE 500000
#define NREL 6
#define SLOPE 0.2f
#define WCAP 4        // register edge capacity per lane (4*64 = 256 edges/wave)

typedef __attribute__((ext_vector_type(4))) float f32x4;
typedef __attribute__((ext_vector_type(8))) short s16x8;
typedef __attribute__((ext_vector_type(4))) short s16x4;
typedef unsigned short u16;
typedef unsigned int u32;

__device__ __forceinline__ u16 f2bf(float v) {
  u32 x = __float_as_uint(v);
  u32 r = (x + 0x7fffu + ((x >> 16) & 1u)) >> 16;  // RNE
  return (u16)r;
}
__device__ __forceinline__ float bf2f(u16 u) {
  return __uint_as_float(((u32)u) << 16);
}

// ---------------------------------------------------------------------------
// Split-precision bf16 MFMA GEMM core, software-pipelined:
// prologue: load tile0 -> regs
// loop: {LDS-write(regs); barrier; issue loads(tile+1); ds_read+MFMA; barrier}
// A staged f32 -> hi/lo bf16 (2 MFMAs per fragment): only weight rounding.
// Tile BM=64, BN=128, BK=64. 256 thr = 4 waves (2x2), wave tile 32x64.
// LDS XOR-swizzle (byte ^= (row&7)<<4); C/D: col=lane&15, row=(lane>>4)*4+reg.
// ---------------------------------------------------------------------------
template<bool BIAS, bool ELU, bool ADD, bool SPLITK>
__device__ __forceinline__ void gemm_core(
    const float* __restrict__ A, const u16* __restrict__ Bt,
    const float* __restrict__ bias, const float* __restrict__ add,
    float* __restrict__ C, int M, int K, int Kp, int kbeg, int kend)
{
  __shared__ char As[64 * 128];
  __shared__ char Aslo[64 * 128];
  __shared__ char Bs[128 * 128];
  const int tid = threadIdx.x;
  const int bm = blockIdx.x * 64;
  const int lane = tid & 63;
  const int wave = tid >> 6;
  const int wr = wave >> 1, wc = wave & 1;
  const int lane16 = lane & 15, lhalf = lane >> 4;

  const int a_row0 = tid >> 4;            // + it*16
  const int a_kc = (tid & 15) << 2;
  const int b_row0 = tid >> 3;            // + it*32
  const int b_kc = (tid & 7) << 3;

  float4 pa[4];
  s16x8 pb[4];

  auto LOAD = [&](int k0) {
    #pragma unroll
    for (int it = 0; it < 4; it++) {
      int gr = bm + a_row0 + it * 16, gk = k0 + a_kc;
      float4 v = make_float4(0.f, 0.f, 0.f, 0.f);
      if (gr < M && gk < K) v = *(const float4*)&A[(size_t)gr * K + gk];
      pa[it] = v;
    }
    #pragma unroll
    for (int it = 0; it < 4; it++) {
      int row = b_row0 + it * 32;
      pb[it] = *(const s16x8*)&Bt[(size_t)row * Kp + k0 + b_kc];
    }
  };

  f32x4 acc[2][4];
  #pragma unroll
  for (int mi = 0; mi < 2; mi++)
    #pragma unroll
    for (int ni = 0; ni < 4; ni++)
      #pragma unroll
      for (int q = 0; q < 4; q++) acc[mi][ni][q] = 0.f;

  LOAD(kbeg);

  for (int k0 = kbeg; k0 < kend; k0 += 64) {
    // ---- regs -> LDS (with hi/lo convert for A) ----
    #pragma unroll
    for (int it = 0; it < 4; it++) {
      int row = a_row0 + it * 16;
      float vv[4] = {pa[it].x, pa[it].y, pa[it].z, pa[it].w};
      s16x4 hi, lo;
      #pragma unroll
      for (int j = 0; j < 4; j++) {
        u16 h = f2bf(vv[j]);
        hi[j] = (short)h;
        lo[j] = (short)f2bf(vv[j] - bf2f(h));
      }
      int boff = row * 128 + ((a_kc * 2) ^ ((row & 7) << 4));
      *(s16x4*)(As + boff) = hi;
      *(s16x4*)(Aslo + boff) = lo;
    }
    #pragma unroll
    for (int it = 0; it < 4; it++) {
      int row = b_row0 + it * 32;
      *(s16x8*)(Bs + row * 128 + ((b_kc * 2) ^ ((row & 7) << 4))) = pb[it];
    }
    __syncthreads();
    // ---- issue next tile's global loads (latency hides under MFMA) ----
    if (k0 + 64 < kend) LOAD(k0 + 64);
    // ---- ds_read + MFMA ----
    #pragma unroll
    for (int kk = 0; kk < 2; kk++) {
      const int kbyte = kk * 64 + lhalf * 16;
      s16x8 afh[2], afl[2], bfr[4];
      #pragma unroll
      for (int mi = 0; mi < 2; mi++) {
        int row = wr * 32 + mi * 16 + lane16;
        int boff = row * 128 + (kbyte ^ ((row & 7) << 4));
        afh[mi] = *(const s16x8*)(As + boff);
        afl[mi] = *(const s16x8*)(Aslo + boff);
      }
      #pragma unroll
      for (int ni = 0; ni < 4; ni++) {
        int row = wc * 64 + ni * 16 + lane16;
        bfr[ni] = *(const s16x8*)(Bs + row * 128 + (kbyte ^ ((row & 7) << 4)));
      }
      #pragma unroll
      for (int mi = 0; mi < 2; mi++)
        #pragma unroll
        for (int ni = 0; ni < 4; ni++) {
          acc[mi][ni] = __builtin_amdgcn_mfma_f32_16x16x32_bf16(
              afl[mi], bfr[ni], acc[mi][ni], 0, 0, 0);
          acc[mi][ni] = __builtin_amdgcn_mfma_f32_16x16x32_bf16(
              afh[mi], bfr[ni], acc[mi][ni], 0, 0, 0);
        }
    }
    __syncthreads();
  }

  float bcol[4];
  #pragma unroll
  for (int ni = 0; ni < 4; ni++) {
    int col = wc * 64 + ni * 16 + lane16;
    if (BIAS) bcol[ni] = bias[col];
  }
  #pragma unroll
  for (int mi = 0; mi < 2; mi++) {
    #pragma unroll
    for (int q = 0; q < 4; q++) {
      int grow = bm + wr * 32 + mi * 16 + lhalf * 4 + q;
      if (grow < M) {
        #pragma unroll
        for (int ni = 0; ni < 4; ni++) {
          float v = acc[mi][ni][q];
          int col = wc * 64 + ni * 16 + lane16;
          if (BIAS) v += bcol[ni];
          if (ADD) v += add[(size_t)grow * 128 + col];
          if (!SPLITK && ELU) v = v > 0.f ? v : expm1f(v);
          C[(size_t)grow * 128 + col] = v;
        }
      }
    }
  }
}

struct GB {
  const float* A[3];
  const u16* Bt[3];
  const float* bias[3];
  const float* add[3];
  float* C[3];
  int K[3];
  int Kp[3];
};

template<bool BIAS, bool ELU, bool ADD>
__global__ __launch_bounds__(256, 2)
void gemm_mfma(GB gb, int M)
{
  int z = blockIdx.z;
  gemm_core<BIAS, ELU, ADD, false>(gb.A[z], gb.Bt[z], gb.bias[z], gb.add[z],
                                   gb.C[z], M, gb.K[z], gb.Kp[z], 0, gb.Kp[z]);
}

struct SK {
  const float* A[3];
  const u16* Bt[3];
  float* C[3];
  int K[3];
  int Kp[3];
};

__global__ __launch_bounds__(256, 2)
void gemm_splitk(SK sk, int M)
{
  int z = blockIdx.z;
  int cb = blockIdx.y * 512;
  if (cb >= sk.Kp[z]) return;
  int kend = (cb + 512 < sk.Kp[z]) ? cb + 512 : sk.Kp[z];
  float* C = sk.C[z] + (size_t)blockIdx.y * M * 128;
  gemm_core<false, false, false, true>(sk.A[z], sk.Bt[z], nullptr, nullptr,
                                       C, M, sk.K[z], sk.Kp[z], cb, kend);
}

struct RP { const float* bias[3]; int nch[3]; };

__global__ __launch_bounds__(256)
void reduce_proj(const float* __restrict__ part, RP rp, float* __restrict__ Xf)
{
  int z = blockIdx.z;
  int i = blockIdx.x * 256 + threadIdx.x;   // over NPER*128
  int c = i & 127;
  int nch = rp.nch[z];
  const float* base = part + (size_t)z * 4 * NPER * 128 + i;
  float s = 0.f;
  for (int ch = 0; ch < nch; ch++) s += base[(size_t)ch * NPER * 128];
  s += rp.bias[z][c];
  Xf[(size_t)z * NPER * 128 + i] = s > 0.f ? s : expm1f(s);
}

// ---------------------------------------------------------------------------
// Weight convert: src f32 [K][128] -> dst bf16 [128][Kp] (transposed, padded)
// ---------------------------------------------------------------------------
struct CW {
  const float* src[9];
  u16* dst[9];
  int K[9];
  int Kp[9];
};

__global__ __launch_bounds__(256)
void conv_w(CW cw) {
  int z = blockIdx.z;
  int K = cw.K[z], Kp = cw.Kp[z];
  int idx = blockIdx.x * 256 + threadIdx.x;
  if (idx >= 128 * Kp) return;
  int kq = idx >> 7, n = idx & 127;
  cw.dst[z][(size_t)n * Kp + kq] =
      (kq < K) ? f2bf(cw.src[z][(size_t)kq * 128 + n]) : (u16)0;
}

// ---------------------------------------------------------------------------
// Attention-score precompute (exact f32): Wq[r]=W[r]@q; QD[r,n]=X[n,:].Wq[r]
// ---------------------------------------------------------------------------
__global__ __launch_bounds__(128)
void wqk_kernel(const float* __restrict__ W, const float* __restrict__ q,
                const float* __restrict__ k, float* __restrict__ wq,
                float* __restrict__ wk)
{
  int r = blockIdx.x;
  int t = threadIdx.x;
  const float* Wr = W + (size_t)r * 128 * 128 + (size_t)t * 128;
  float aq = 0.f, ak = 0.f;
  for (int o = 0; o < 128; o++) {
    float w = Wr[o];
    aq = fmaf(w, q[o], aq);
    ak = fmaf(w, k[o], ak);
  }
  wq[r * 128 + t] = aq;
  wk[r * 128 + t] = ak;
}

__global__ __launch_bounds__(256)
void qdkd_kernel(const float* __restrict__ Xf, const float* __restrict__ wq,
                 const float* __restrict__ wk, float* __restrict__ QD,
                 float* __restrict__ KD)
{
  __shared__ float sq[NREL * 128], sk[NREL * 128];
  for (int i = threadIdx.x; i < NREL * 128; i += 256) { sq[i] = wq[i]; sk[i] = wk[i]; }
  __syncthreads();
  int n = blockIdx.x * 256 + threadIdx.x;
  if (n >= N_TOTAL) return;
  float aq[NREL], ak[NREL];
  #pragma unroll
  for (int r = 0; r < NREL; r++) { aq[r] = 0.f; ak[r] = 0.f; }
  for (int kc = 0; kc < 128; kc += 4) {
    float4 x = *(const float4*)&Xf[(size_t)n * 128 + kc];
    #pragma unroll
    for (int r = 0; r < NREL; r++) {
      aq[r] += x.x * sq[r * 128 + kc] + x.y * sq[r * 128 + kc + 1]
             + x.z * sq[r * 128 + kc + 2] + x.w * sq[r * 128 + kc + 3];
      ak[r] += x.x * sk[r * 128 + kc] + x.y * sk[r * 128 + kc + 1]
             + x.z * sk[r * 128 + kc + 2] + x.w * sk[r * 128 + kc + 3];
    }
  }
  #pragma unroll
  for (int r = 0; r < NREL; r++) {
    QD[(size_t)r * N_TOTAL + n] = aq[r];
    KD[(size_t)r * N_TOTAL + n] = ak[r];
  }
}

// ---------------------------------------------------------------------------
// CSR build; edge_fill writes CSR-ordered packed meta: src | (t<<15)
// ---------------------------------------------------------------------------
__global__ __launch_bounds__(256)
void edge_count(const int* __restrict__ dst, int* __restrict__ cnt) {
  int e = blockIdx.x * 256 + threadIdx.x;
  if (e < NEDGE) atomicAdd(&cnt[dst[e]], 1);
}

__global__ __launch_bounds__(1024)
void scan_kernel(const int* __restrict__ cnt, int* __restrict__ off,
                 int* __restrict__ cur) {
  __shared__ int ps[1024];
  const int t = threadIdx.x;
  const int CH = (N_TOTAL + 1023) / 1024;
  const int base = t * CH;
  int s = 0;
  for (int i = 0; i < CH; i++) {
    int idx = base + i;
    if (idx < N_TOTAL) s += cnt[idx];
  }
  ps[t] = s;
  __syncthreads();
  for (int o = 1; o < 1024; o <<= 1) {
    int v = (t >= o) ? ps[t - o] : 0;
    __syncthreads();
    ps[t] += v;
    __syncthreads();
  }
  int run = ps[t] - s;
  for (int i = 0; i < CH; i++) {
    int idx = base + i;
    if (idx < N_TOTAL) {
      off[idx] = run; cur[idx] = run;
      run += cnt[idx];
    }
  }
  if (t == 1023) off[N_TOTAL] = run;
}

__global__ __launch_bounds__(256)
void edge_fill(const int* __restrict__ dst, const int* __restrict__ src,
               const int* __restrict__ et, int* __restrict__ cur,
               int* __restrict__ meta) {
  int e = blockIdx.x * 256 + threadIdx.x;
  if (e >= NEDGE) return;
  int p = atomicAdd(&cur[dst[e]], 1);
  meta[p] = src[e] | (et[e] << 15);
}

// ---------------------------------------------------------------------------
// Wave-per-destination attention + per-relation aggregation. No LDS, no
// barriers: alpha/meta in registers (<=256 edges), shfl reductions, shfl
// broadcast in the gather phase. agg[d][r][128] output.
// ---------------------------------------------------------------------------
__global__ __launch_bounds__(256)
void csr_aggw(const int* __restrict__ off, const int* __restrict__ meta,
              const float* __restrict__ qd, const float* __restrict__ kd,
              const float* __restrict__ xrow, float* __restrict__ agg)
{
  const int d = blockIdx.x * 4 + (threadIdx.x >> 6);
  const int lane = threadIdx.x & 63;
  if (d >= N_TOTAL) return;
  const int n0 = off[d];
  const int deg = off[d + 1] - n0;

  float2 accr[NREL];
  #pragma unroll
  for (int r = 0; r < NREL; r++) accr[r] = make_float2(0.f, 0.f);

  float qrow[NREL];
  #pragma unroll
  for (int r = 0; r < NREL; r++) qrow[r] = qd[r * N_TOTAL + d];

  if (deg > 0) {
    if (deg <= 64 * WCAP) {
      int mreg[WCAP];
      float areg[WCAP];
      const int nc = (deg + 63) >> 6;
      float lmax = -3.0e38f;
      #pragma unroll
      for (int c = 0; c < WCAP; c++) {
        mreg[c] = 0; areg[c] = -3.0e38f;
        int i = c * 64 + lane;
        if (c < nc && i < deg) {
          int mm = meta[n0 + i];
          int s_ = mm & 0x7FFF, t = mm >> 15;
          float a = qrow[t] + kd[t * N_TOTAL + s_];
          a = (a > 0.f) ? a : SLOPE * a;
          mreg[c] = mm; areg[c] = a;
          lmax = fmaxf(lmax, a);
        }
      }
      #pragma unroll
      for (int m = 32; m; m >>= 1) lmax = fmaxf(lmax, __shfl_xor(lmax, m));
      float lsum = 0.f;
      #pragma unroll
      for (int c = 0; c < WCAP; c++) {
        int i = c * 64 + lane;
        if (c < nc && i < deg) {
          areg[c] = expf(areg[c] - lmax);
          lsum += areg[c];
        }
      }
      #pragma unroll
      for (int m = 32; m; m >>= 1) lsum += __shfl_xor(lsum, m);
      const float scale = (float)deg / lsum;
      // gather: broadcast coef+meta per edge, float2 row read per lane
      for (int i = 0; i < deg; i++) {
        int c = i >> 6, l = i & 63;
        float cf = 0.f; int mm = 0;
        #pragma unroll
        for (int cc = 0; cc < WCAP; cc++) {
          if (cc == c) { cf = __shfl(areg[cc], l); mm = __shfl(mreg[cc], l); }
        }
        cf *= scale;
        int s_ = mm & 0x7FFF, t = mm >> 15;
        float2 v = *(const float2*)&xrow[(size_t)s_ * 128 + lane * 2];
        float2 cv = make_float2(cf * v.x, cf * v.y);
        #pragma unroll
        for (int r = 0; r < NREL; r++) {
          bool hit = (t == r);
          accr[r].x += hit ? cv.x : 0.f;
          accr[r].y += hit ? cv.y : 0.f;
        }
      }
    } else {
      // uniform fallback (deg > 256): every lane redundantly scans scores
      float m = -3.0e38f;
      for (int i = 0; i < deg; i++) {
        int mm = meta[n0 + i];
        int s_ = mm & 0x7FFF, t = mm >> 15;
        float a = qrow[t] + kd[t * N_TOTAL + s_];
        a = (a > 0.f) ? a : SLOPE * a;
        m = fmaxf(m, a);
      }
      float ssum = 0.f;
      for (int i = 0; i < deg; i++) {
        int mm = meta[n0 + i];
        int s_ = mm & 0x7FFF, t = mm >> 15;
        float a = qrow[t] + kd[t * N_TOTAL + s_];
        a = (a > 0.f) ? a : SLOPE * a;
        ssum += expf(a - m);
      }
      const float scale = (float)deg / ssum;
      for (int i = 0; i < deg; i++) {
        int mm = meta[n0 + i];
        int s_ = mm & 0x7FFF, t = mm >> 15;
        float a = qrow[t] + kd[t * N_TOTAL + s_];
        a = (a > 0.f) ? a : SLOPE * a;
        float cf = expf(a - m) * scale;
        float2 v = *(const float2*)&xrow[(size_t)s_ * 128 + lane * 2];
        float2 cv = make_float2(cf * v.x, cf * v.y);
        #pragma unroll
        for (int r = 0; r < NREL; r++) {
          bool hit = (t == r);
          accr[r].x += hit ? cv.x : 0.f;
          accr[r].y += hit ? cv.y : 0.f;
        }
      }
    }
  }
  #pragma unroll
  for (int r = 0; r < NREL; r++)
    *(float2*)&agg[((size_t)d * NREL + r) * 128 + lane * 2] = accr[r];
}

__global__ __launch_bounds__(256)
void lin2_kernel(const float* __restrict__ z, const float* __restrict__ W,
                 const float* __restrict__ b, float* __restrict__ out)
{
  int row = blockIdx.x * 4 + (threadIdx.x >> 6);
  int lane = threadIdx.x & 63;
  if (row >= NPER) return;
  float p[5] = {0.f, 0.f, 0.f, 0.f, 0.f};
  #pragma unroll
  for (int h = 0; h < 2; h++) {
    int kidx = lane + h * 64;
    float zv = z[(size_t)row * 128 + kidx];
    #pragma unroll
    for (int j = 0; j < 5; j++) p[j] = fmaf(zv, W[kidx * 5 + j], p[j]);
  }
  #pragma unroll
  for (int mm = 32; mm; mm >>= 1)
    #pragma unroll
    for (int j = 0; j < 5; j++) p[j] += __shfl_xor(p[j], mm);
  if (lane == 0) {
    #pragma unroll
    for (int j = 0; j < 5; j++) out[(size_t)row * 5 + j] = p[j] + b[j];
  }
}

// ---------------------------------------------------------------------------
extern "C" void kernel_launch(void* const* d_in, const int* in_sizes, int n_in,
                              void* d_out, int out_size, void* d_ws, size_t ws_size,
                              hipStream_t stream) {
  const float* xs[3] = {(const float*)d_in[0], (const float*)d_in[1], (const float*)d_in[2]};
  const float* projW[3] = {(const float*)d_in[3], (const float*)d_in[5], (const float*)d_in[7]};
  const float* projb[3] = {(const float*)d_in[4], (const float*)d_in[6], (const float*)d_in[8]};
  const float* slW[3]   = {(const float*)d_in[9], (const float*)d_in[11], (const float*)d_in[13]};
  const float* slb[3]   = {(const float*)d_in[10], (const float*)d_in[12], (const float*)d_in[14]};
  const float* W1 = (const float*)d_in[15];
  const float* q1 = (const float*)d_in[16];
  const float* k1 = (const float*)d_in[17];
  const float* b1 = (const float*)d_in[18];
  const float* W2 = (const float*)d_in[19];
  const float* q2 = (const float*)d_in[20];
  const float* k2 = (const float*)d_in[21];
  const float* b2 = (const float*)d_in[22];
  const float* lin1W = (const float*)d_in[23];
  const float* lin1b = (const float*)d_in[24];
  const float* lin2W = (const float*)d_in[25];
  const float* lin2b = (const float*)d_in[26];
  const int* esrc = (const int*)d_in[27];
  const int* edst = (const int*)d_in[28];
  const int* etyp = (const int*)d_in[29];

  char* wp = (char*)d_ws;
  auto alloc = [&](size_t bytes) -> char* {
    char* p = wp; wp += (bytes + 255) & ~(size_t)255; return p;
  };
  float* Xf  = (float*)alloc((size_t)N_TOTAL * 128 * 4);
  float* SL  = (float*)alloc((size_t)N_TOTAL * 128 * 4);
  float* Hf  = (float*)alloc((size_t)N_TOTAL * 128 * 4);
  float* QD  = (float*)alloc((size_t)NREL * N_TOTAL * 4);
  float* KD  = (float*)alloc((size_t)NREL * N_TOTAL * 4);
  float* Z   = (float*)alloc((size_t)NPER * 128 * 4);
  float* WQ1 = (float*)alloc((size_t)NREL * 128 * 4);
  float* WK1 = (float*)alloc((size_t)NREL * 128 * 4);
  float* WQ2 = (float*)alloc((size_t)NREL * 128 * 4);
  float* WK2 = (float*)alloc((size_t)NREL * 128 * 4);
  int*   CNT = (int*)  alloc((size_t)N_TOTAL * 4);
  int*   OFF = (int*)  alloc((size_t)(N_TOTAL + 1) * 4);
  int*   CUR = (int*)  alloc((size_t)N_TOTAL * 4);
  int*   META= (int*)  alloc((size_t)NEDGE * 4);

  // AGG [30000][768] f32 (92 MB); region doubles as split-K PART
  // [3][4][NPER][128] f32 (61 MB) — PART dead before csr_aggw runs.
  float* AGG  = (float*)alloc((size_t)N_TOTAL * NREL * 128 * 4);
  float* PART = AGG;

  CW cw;
  int nW = 0;
  auto addW = [&](const float* src, int K) {
    int Kp = (K + 63) & ~63;
    cw.src[nW] = src; cw.K[nW] = K; cw.Kp[nW] = Kp;
    cw.dst[nW] = (u16*)alloc((size_t)128 * Kp * 2);
    nW++;
  };
  addW(projW[0], 2000); addW(projW[1], 1500); addW(projW[2], 1000);  // 0-2
  addW(slW[0], 128); addW(slW[1], 128); addW(slW[2], 128);           // 3-5
  addW(W1, NREL * 128);   // 6: stacked [768][128] -> Bt [128][768]
  addW(W2, NREL * 128);   // 7
  addW(lin1W, 128);       // 8

  const int gridM_per = (NPER + 63) / 64;     // 157
  const int gridM_tot = (N_TOTAL + 63) / 64;  // 469
  const int gridE = (NEDGE + 255) / 256;

  // ---- CSR build ----
  hipMemsetAsync(CNT, 0, (size_t)N_TOTAL * 4, stream);
  edge_count<<<gridE, 256, 0, stream>>>(edst, CNT);
  scan_kernel<<<1, 1024, 0, stream>>>(CNT, OFF, CUR);
  edge_fill<<<gridE, 256, 0, stream>>>(edst, esrc, etyp, CUR, META);

  conv_w<<<dim3(1024, 1, 9), 256, 0, stream>>>(cw);
  wqk_kernel<<<NREL, 128, 0, stream>>>(W1, q1, k1, WQ1, WK1);
  wqk_kernel<<<NREL, 128, 0, stream>>>(W2, q2, k2, WQ2, WK2);

  // ---- projections via split-K (chunks of 512) ----
  {
    SK sk;
    for (int z = 0; z < 3; z++) {
      sk.A[z] = xs[z]; sk.Bt[z] = cw.dst[z];
      sk.C[z] = PART + (size_t)z * 4 * NPER * 128;
      sk.K[z] = cw.K[z]; sk.Kp[z] = cw.Kp[z];
    }
    gemm_splitk<<<dim3(gridM_per, 4, 3), 256, 0, stream>>>(sk, NPER);
    RP rp;
    for (int z = 0; z < 3; z++) { rp.bias[z] = projb[z]; rp.nch[z] = cw.Kp[z] / 512; }
    reduce_proj<<<dim3(NPER * 128 / 256, 1, 3), 256, 0, stream>>>(PART, rp, Xf);
  }
  // ---- self-loops: SL = Xf_i @ slW_i + slb_i ----
  {
    GB g;
    for (int z = 0; z < 3; z++) {
      g.A[z] = Xf + (size_t)z * NPER * 128; g.Bt[z] = cw.dst[3 + z];
      g.bias[z] = slb[z]; g.add[z] = nullptr;
      g.C[z] = SL + (size_t)z * NPER * 128;
      g.K[z] = 128; g.Kp[z] = 128;
    }
    gemm_mfma<true, false, false><<<dim3(gridM_per, 1, 3), 256, 0, stream>>>(g, NPER);
  }

  for (int layer = 0; layer < 2; layer++) {
    const float* Ain = (layer == 0) ? Xf : Hf;
    const float* WQ = (layer == 0) ? WQ1 : WQ2;
    const float* WK = (layer == 0) ? WK1 : WK2;
    const float* bb = (layer == 0) ? b1 : b2;
    const u16* Wstk = cw.dst[6 + layer];

    qdkd_kernel<<<(N_TOTAL + 255) / 256, 256, 0, stream>>>(Ain, WQ, WK, QD, KD);
    csr_aggw<<<(N_TOTAL + 3) / 4, 256, 0, stream>>>(OFF, META, QD, KD, Ain, AGG);
    // transform: Hf = elu(AGG[30000,768] @ Wstack[768,128] + b + SL)
    GB g;
    g.A[0] = AGG; g.Bt[0] = Wstk; g.bias[0] = bb; g.add[0] = SL; g.C[0] = Hf;
    g.K[0] = NREL * 128; g.Kp[0] = NREL * 128;
    gemm_mfma<true, true, true><<<dim3(gridM_tot, 1, 1), 256, 0, stream>>>(g, N_TOTAL);
  }

  // ---- head ----
  {
    GB g;
    g.A[0] = Hf; g.Bt[0] = cw.dst[8]; g.bias[0] = lin1b; g.add[0] = nullptr; g.C[0] = Z;
    g.K[0] = 128; g.Kp[0] = 128;
    gemm_mfma<true, true, false><<<dim3(gridM_per, 1, 1), 256, 0, stream>>>(g, NPER);
  }
  lin2_kernel<<<(NPER + 3) / 4, 256, 0, stream>>>(Z, lin2W, lin2b, (float*)d_out);
}